// Round 1
// baseline (414.732 us; speedup 1.0000x reference)
//
#include <hip/hip_runtime.h>
#include <math.h>

#define N_TOK 13824
#define DM 192
#define DI 384
#define DS 16
#define DTR 12
#define CHUNK 32
#define NCHUNK 432   // 13824 / 32

__device__ __forceinline__ float sigmoidf_(float x){ return 1.f/(1.f+__expf(-x)); }

// ---------------- Kernel 1: LayerNorm(x) @ W_in -> xs, z ----------------
// 8 tokens per block, 256 threads. Each thread owns 3 output columns.
__global__ __launch_bounds__(256) void k1_ln_gemm1(
    const float* __restrict__ x, const float* __restrict__ lnw,
    const float* __restrict__ lnb, const float* __restrict__ Win,
    float* __restrict__ xs, float* __restrict__ z)
{
  __shared__ float lx[8][192];
  __shared__ float mu[8], rs[8];
  const int tid = threadIdx.x;
  const int tok0 = blockIdx.x * 8;
  for (int i = tid; i < 8*192; i += 256)
    lx[i/192][i%192] = x[(size_t)tok0*192 + i];
  __syncthreads();
  {
    int g = tid >> 5, l = tid & 31;
    float s = 0.f, s2 = 0.f;
    for (int k = l; k < 192; k += 32) { float v = lx[g][k]; s += v; s2 += v*v; }
    #pragma unroll
    for (int off = 16; off > 0; off >>= 1) {
      s  += __shfl_down(s,  off, 32);
      s2 += __shfl_down(s2, off, 32);
    }
    if (l == 0) {
      float m = s * (1.f/192.f);
      float v = s2 * (1.f/192.f) - m*m;
      mu[g] = m; rs[g] = rsqrtf(v + 1e-5f);
    }
  }
  __syncthreads();
  for (int i = tid; i < 8*192; i += 256) {
    int t = i/192, k = i%192;
    lx[t][k] = (lx[t][k]-mu[t])*rs[t]*lnw[k] + lnb[k];
  }
  __syncthreads();

  float acc[8][3];
  #pragma unroll
  for (int t=0;t<8;t++){acc[t][0]=0.f;acc[t][1]=0.f;acc[t][2]=0.f;}
  for (int k4 = 0; k4 < 48; k4++) {
    const int k = k4*4;
    float wv[4][3];
    #pragma unroll
    for (int kk=0;kk<4;kk++){
      wv[kk][0]=Win[(size_t)(k+kk)*768 + tid      ];
      wv[kk][1]=Win[(size_t)(k+kk)*768 + tid + 256];
      wv[kk][2]=Win[(size_t)(k+kk)*768 + tid + 512];
    }
    #pragma unroll
    for (int t=0;t<8;t++){
      float4 lv = *(const float4*)&lx[t][k];
      #pragma unroll
      for (int j=0;j<3;j++)
        acc[t][j] = fmaf(lv.x,wv[0][j], fmaf(lv.y,wv[1][j], fmaf(lv.z,wv[2][j], fmaf(lv.w,wv[3][j], acc[t][j]))));
    }
  }
  #pragma unroll
  for (int t=0;t<8;t++){
    size_t n = tok0 + t;
    xs[n*384 + tid] = acc[t][0];                 // c0 in [0,256)
    int c1 = tid + 256;                          // c1 in [256,512)
    if (c1 < 384) xs[n*384 + c1] = acc[t][1];
    else          z [n*384 + c1-384] = acc[t][1];
    z[n*384 + tid + 128] = acc[t][2];            // c2 = tid+512 -> z col tid+128
  }
}

// ---------------- Kernel 2: depthwise conv3 over N + SiLU -> u ----------------
__global__ __launch_bounds__(256) void k2_conv_silu(
    const float* __restrict__ xs, const float* __restrict__ cw,
    const float* __restrict__ cb, float* __restrict__ u)
{
  const int idx = blockIdx.x*256 + threadIdx.x;   // 0 .. N_TOK*96-1
  const int d4 = idx % 96;
  const int n  = idx / 96;
  const float4* x4 = (const float4*)xs;
  float4 cc = x4[(size_t)n*96 + d4];
  float4 mm = make_float4(0.f,0.f,0.f,0.f), pp = make_float4(0.f,0.f,0.f,0.f);
  if (n > 0)         mm = x4[(size_t)(n-1)*96 + d4];
  if (n < N_TOK-1)   pp = x4[(size_t)(n+1)*96 + d4];
  float m[4]={mm.x,mm.y,mm.z,mm.w}, c[4]={cc.x,cc.y,cc.z,cc.w}, p[4]={pp.x,pp.y,pp.z,pp.w};
  float o[4];
  #pragma unroll
  for (int j=0;j<4;j++){
    int d = d4*4 + j;
    float v = fmaf(cw[d*3+0], m[j], fmaf(cw[d*3+1], c[j], fmaf(cw[d*3+2], p[j], cb[d])));
    o[j] = v * sigmoidf_(v);
  }
  *(float4*)&u[(size_t)n*384 + d4*4] = make_float4(o[0],o[1],o[2],o[3]);
}

// ---------------- Kernel 3: dbl = u @ x_proj_w; delta = softplus(dt@dt_w+dt_b) ----------------
__global__ __launch_bounds__(384) void k3_xproj(
    const float* __restrict__ u, const float* __restrict__ xpw,
    const float* __restrict__ dtw, const float* __restrict__ dtb,
    float* __restrict__ delta, float* __restrict__ Bc, float* __restrict__ Cc)
{
  __shared__ float su[384];
  __shared__ float sdbl[44];
  const int tid = threadIdx.x; const size_t n = blockIdx.x;
  su[tid] = u[n*384 + tid];
  __syncthreads();
  if (tid < 352) {
    int j = tid >> 3, r = tid & 7;
    float p = 0.f;
    for (int k = r; k < 384; k += 8) p = fmaf(su[k], xpw[k*44 + j], p);
    p += __shfl_down(p, 4, 8);
    p += __shfl_down(p, 2, 8);
    p += __shfl_down(p, 1, 8);
    if (r == 0) sdbl[j] = p;
  }
  __syncthreads();
  float acc = dtb[tid];
  #pragma unroll
  for (int r = 0; r < 12; r++) acc = fmaf(sdbl[r], dtw[r*384 + tid], acc);
  float sp = fmaxf(acc, 0.f) + log1pf(__expf(-fabsf(acc)));   // stable softplus
  delta[n*384 + tid] = sp;
  if (tid < 16) { Bc[n*16 + tid] = sdbl[12 + tid]; Cc[n*16 + tid] = sdbl[28 + tid]; }
}

// ---------------- Kernel 4: scan phase 1 (per-chunk product + partial state) ----------------
__global__ __launch_bounds__(384) void k4_scan1(
    const float* __restrict__ delta, const float* __restrict__ u,
    const float* __restrict__ Bc, const float* __restrict__ Alog,
    float* __restrict__ P, float* __restrict__ he)
{
  __shared__ float sB[CHUNK][16];
  const int tid = threadIdx.x; const int c = blockIdx.x; const int n0 = c*CHUNK;
  for (int i = tid; i < CHUNK*16; i += 384) sB[i>>4][i&15] = Bc[(size_t)n0*16 + i];
  float Ac[16];
  #pragma unroll
  for (int s=0;s<16;s++) Ac[s] = -__expf(Alog[tid*16+s]);
  __syncthreads();
  float h[16], Pm[16];
  #pragma unroll
  for (int s=0;s<16;s++){ h[s]=0.f; Pm[s]=1.f; }
  for (int nn=0; nn<CHUNK; nn++){
    size_t n = n0 + nn;
    float dl = delta[n*384 + tid];
    float du = dl * u[n*384 + tid];
    #pragma unroll
    for (int s=0;s<16;s++){
      float a = __expf(dl * Ac[s]);
      h[s] = fmaf(a, h[s], du * sB[nn][s]);
      Pm[s] *= a;
    }
  }
  size_t base = (size_t)c*6144 + (size_t)tid*16;
  #pragma unroll
  for (int s=0;s<16;s+=4){
    *(float4*)&P [base+s] = make_float4(Pm[s],Pm[s+1],Pm[s+2],Pm[s+3]);
    *(float4*)&he[base+s] = make_float4(h[s], h[s+1], h[s+2], h[s+3]);
  }
}

// ---------------- Kernel 5: scan phase 2 (cross-chunk prefix) ----------------
__global__ __launch_bounds__(256) void k5_scan2(
    const float* __restrict__ P, const float* __restrict__ he, float* __restrict__ hi)
{
  const int idx = blockIdx.x*256 + threadIdx.x;   // 0..6143
  float H = 0.f;
  for (int c = 0; c < NCHUNK; c++){
    size_t o = (size_t)c*6144 + idx;
    hi[o] = H;
    H = fmaf(P[o], H, he[o]);
  }
}

// ---------------- Kernel 6: scan phase 3 (re-scan with correct init, emit y) ----------------
__global__ __launch_bounds__(384) void k6_scan3(
    const float* __restrict__ delta, const float* __restrict__ u,
    const float* __restrict__ Bc, const float* __restrict__ Cc,
    const float* __restrict__ Alog, const float* __restrict__ Dp,
    const float* __restrict__ hi, float* __restrict__ y)
{
  __shared__ float sB[CHUNK][16], sC[CHUNK][16];
  const int tid = threadIdx.x; const int c = blockIdx.x; const int n0 = c*CHUNK;
  for (int i = tid; i < CHUNK*16; i += 384){
    sB[i>>4][i&15] = Bc[(size_t)n0*16 + i];
    sC[i>>4][i&15] = Cc[(size_t)n0*16 + i];
  }
  float Ac[16];
  #pragma unroll
  for (int s=0;s<16;s++) Ac[s] = -__expf(Alog[tid*16+s]);
  float h[16];
  size_t base = (size_t)c*6144 + (size_t)tid*16;
  #pragma unroll
  for (int s=0;s<16;s+=4){
    float4 hv = *(const float4*)&hi[base+s];
    h[s]=hv.x; h[s+1]=hv.y; h[s+2]=hv.z; h[s+3]=hv.w;
  }
  float Dpd = Dp[tid];
  __syncthreads();
  for (int nn=0; nn<CHUNK; nn++){
    size_t n = n0 + nn;
    float dl = delta[n*384 + tid];
    float uu = u[n*384 + tid];
    float du = dl * uu;
    float acc = uu * Dpd;
    #pragma unroll
    for (int s=0;s<16;s++){
      float a = __expf(dl * Ac[s]);
      h[s] = fmaf(a, h[s], du * sB[nn][s]);
      acc = fmaf(h[s], sC[nn][s], acc);
    }
    y[n*384 + tid] = acc;
  }
}

// ---------------- Kernel 7: LayerNorm(y) * silu(z) -> g ----------------
__global__ __launch_bounds__(384) void k7_lngate(
    const float* __restrict__ y, const float* __restrict__ z,
    const float* __restrict__ lnw, const float* __restrict__ lnb,
    float* __restrict__ g)
{
  const int tid = threadIdx.x; const size_t n = blockIdx.x;
  float yv = y[n*384 + tid], zv = z[n*384 + tid];
  float s = yv, s2 = yv*yv;
  #pragma unroll
  for (int off = 32; off > 0; off >>= 1){
    s  += __shfl_xor(s,  off);
    s2 += __shfl_xor(s2, off);
  }
  __shared__ float wsum[6], wsum2[6];
  __shared__ float smu, srs;
  int w = tid >> 6;
  if ((tid & 63) == 0){ wsum[w] = s; wsum2[w] = s2; }
  __syncthreads();
  if (tid == 0){
    float S=0.f, S2=0.f;
    #pragma unroll
    for (int i=0;i<6;i++){ S += wsum[i]; S2 += wsum2[i]; }
    float m = S * (1.f/384.f);
    float v = S2 * (1.f/384.f) - m*m;
    smu = m; srs = rsqrtf(v + 1e-5f);
  }
  __syncthreads();
  float ly = (yv - smu)*srs*lnw[tid] + lnb[tid];
  g[n*384 + tid] = ly * zv * sigmoidf_(zv);
}

// ---------------- Kernel 8: out = g @ W_out + x ----------------
__global__ __launch_bounds__(192) void k8_gemm2(
    const float* __restrict__ g, const float* __restrict__ Wout,
    const float* __restrict__ x, float* __restrict__ out)
{
  __shared__ float sg[8][384];
  const int tid = threadIdx.x; const int tok0 = blockIdx.x*8;
  for (int i = tid; i < 8*384; i += 192) sg[i/384][i%384] = g[(size_t)tok0*384 + i];
  __syncthreads();
  float acc[8] = {0.f,0.f,0.f,0.f,0.f,0.f,0.f,0.f};
  for (int k4 = 0; k4 < 96; k4++){
    const int k = k4*4;
    float w0 = Wout[(size_t)(k+0)*192 + tid];
    float w1 = Wout[(size_t)(k+1)*192 + tid];
    float w2 = Wout[(size_t)(k+2)*192 + tid];
    float w3 = Wout[(size_t)(k+3)*192 + tid];
    #pragma unroll
    for (int t=0;t<8;t++){
      float4 gv = *(const float4*)&sg[t][k];
      acc[t] = fmaf(gv.x,w0, fmaf(gv.y,w1, fmaf(gv.z,w2, fmaf(gv.w,w3, acc[t]))));
    }
  }
  #pragma unroll
  for (int t=0;t<8;t++){
    size_t n = tok0 + t;
    out[n*192 + tid] = acc[t] + x[n*192 + tid];
  }
}

extern "C" void kernel_launch(void* const* d_in, const int* in_sizes, int n_in,
                              void* d_out, int out_size, void* d_ws, size_t ws_size,
                              hipStream_t stream) {
  const float* x      = (const float*)d_in[0];
  const float* ln_in_w= (const float*)d_in[1];
  const float* ln_in_b= (const float*)d_in[2];
  const float* W_in   = (const float*)d_in[3];
  const float* conv_w = (const float*)d_in[4];
  const float* conv_b = (const float*)d_in[5];
  const float* xpw    = (const float*)d_in[6];
  const float* dt_w   = (const float*)d_in[7];
  const float* dt_b   = (const float*)d_in[8];
  const float* A_log  = (const float*)d_in[9];
  const float* Dp     = (const float*)d_in[10];
  const float* ln_o_w = (const float*)d_in[11];
  const float* ln_o_b = (const float*)d_in[12];
  const float* W_out  = (const float*)d_in[13];
  float* out = (float*)d_out;

  float* ws = (float*)d_ws;
  const size_t NDI = (size_t)N_TOK * DI;       // 5,308,416
  float* xs   = ws;                 // N x 384   (reused as y by k6)
  float* z    = xs + NDI;           // N x 384
  float* u    = z  + NDI;           // N x 384   (reused as g by k7)
  float* dl   = u  + NDI;           // N x 384
  float* Bc   = dl + NDI;           // N x 16
  float* Cc   = Bc + (size_t)N_TOK*DS;
  float* P    = Cc + (size_t)N_TOK*DS;          // NCHUNK x 6144
  float* he   = P  + (size_t)NCHUNK*DI*DS;
  float* hi   = he + (size_t)NCHUNK*DI*DS;

  k1_ln_gemm1<<<N_TOK/8, 256, 0, stream>>>(x, ln_in_w, ln_in_b, W_in, xs, z);
  k2_conv_silu<<<(N_TOK*96)/256, 256, 0, stream>>>(xs, conv_w, conv_b, u);
  k3_xproj<<<N_TOK, 384, 0, stream>>>(u, xpw, dt_w, dt_b, dl, Bc, Cc);
  k4_scan1<<<NCHUNK, 384, 0, stream>>>(dl, u, Bc, A_log, P, he);
  k5_scan2<<<24, 256, 0, stream>>>(P, he, hi);
  k6_scan3<<<NCHUNK, 384, 0, stream>>>(dl, u, Bc, Cc, A_log, Dp, hi, xs /*y*/);
  k7_lngate<<<N_TOK, 384, 0, stream>>>(xs /*y*/, z, ln_o_w, ln_o_b, u /*g*/);
  k8_gemm2<<<N_TOK/8, 192, 0, stream>>>(u /*g*/, W_out, x, out);
}

// Round 2
// 358.892 us; speedup vs baseline: 1.1556x; 1.1556x over previous
//
#include <hip/hip_runtime.h>
#include <math.h>

#define N_TOK 13824
#define DM 192
#define DI 384
#define DS 16
#define DTR 12
#define CHUNK 32
#define NCHUNK 432   // 13824 / 32

__device__ __forceinline__ float sigmoidf_(float x){ return 1.f/(1.f+__expf(-x)); }

// ---------------- Kernel 1: LayerNorm(x) @ W_in -> xs, z ----------------
// 8 tokens per block, 256 threads. Each thread owns 3 output columns.
__global__ __launch_bounds__(256) void k1_ln_gemm1(
    const float* __restrict__ x, const float* __restrict__ lnw,
    const float* __restrict__ lnb, const float* __restrict__ Win,
    float* __restrict__ xs, float* __restrict__ z)
{
  __shared__ float lx[8][192];
  __shared__ float mu[8], rs[8];
  const int tid = threadIdx.x;
  const int tok0 = blockIdx.x * 8;
  for (int i = tid; i < 8*192; i += 256)
    lx[i/192][i%192] = x[(size_t)tok0*192 + i];
  __syncthreads();
  {
    int g = tid >> 5, l = tid & 31;
    float s = 0.f, s2 = 0.f;
    for (int k = l; k < 192; k += 32) { float v = lx[g][k]; s += v; s2 += v*v; }
    #pragma unroll
    for (int off = 16; off > 0; off >>= 1) {
      s  += __shfl_down(s,  off, 32);
      s2 += __shfl_down(s2, off, 32);
    }
    if (l == 0) {
      float m = s * (1.f/192.f);
      float v = s2 * (1.f/192.f) - m*m;
      mu[g] = m; rs[g] = rsqrtf(v + 1e-5f);
    }
  }
  __syncthreads();
  for (int i = tid; i < 8*192; i += 256) {
    int t = i/192, k = i%192;
    lx[t][k] = (lx[t][k]-mu[t])*rs[t]*lnw[k] + lnb[k];
  }
  __syncthreads();

  float acc[8][3];
  #pragma unroll
  for (int t=0;t<8;t++){acc[t][0]=0.f;acc[t][1]=0.f;acc[t][2]=0.f;}
  for (int k4 = 0; k4 < 48; k4++) {
    const int k = k4*4;
    float wv[4][3];
    #pragma unroll
    for (int kk=0;kk<4;kk++){
      wv[kk][0]=Win[(size_t)(k+kk)*768 + tid      ];
      wv[kk][1]=Win[(size_t)(k+kk)*768 + tid + 256];
      wv[kk][2]=Win[(size_t)(k+kk)*768 + tid + 512];
    }
    #pragma unroll
    for (int t=0;t<8;t++){
      float4 lv = *(const float4*)&lx[t][k];
      #pragma unroll
      for (int j=0;j<3;j++)
        acc[t][j] = fmaf(lv.x,wv[0][j], fmaf(lv.y,wv[1][j], fmaf(lv.z,wv[2][j], fmaf(lv.w,wv[3][j], acc[t][j]))));
    }
  }
  #pragma unroll
  for (int t=0;t<8;t++){
    size_t n = tok0 + t;
    xs[n*384 + tid] = acc[t][0];                 // c0 in [0,256)
    int c1 = tid + 256;                          // c1 in [256,512)
    if (c1 < 384) xs[n*384 + c1] = acc[t][1];
    else          z [n*384 + c1-384] = acc[t][1];
    z[n*384 + tid + 128] = acc[t][2];            // c2 = tid+512 -> z col tid+128
  }
}

// ---------------- Kernel 2: depthwise conv3 over N + SiLU -> u ----------------
__global__ __launch_bounds__(256) void k2_conv_silu(
    const float* __restrict__ xs, const float* __restrict__ cw,
    const float* __restrict__ cb, float* __restrict__ u)
{
  const int idx = blockIdx.x*256 + threadIdx.x;   // 0 .. N_TOK*96-1
  const int d4 = idx % 96;
  const int n  = idx / 96;
  const float4* x4 = (const float4*)xs;
  float4 cc = x4[(size_t)n*96 + d4];
  float4 mm = make_float4(0.f,0.f,0.f,0.f), pp = make_float4(0.f,0.f,0.f,0.f);
  if (n > 0)         mm = x4[(size_t)(n-1)*96 + d4];
  if (n < N_TOK-1)   pp = x4[(size_t)(n+1)*96 + d4];
  float m[4]={mm.x,mm.y,mm.z,mm.w}, c[4]={cc.x,cc.y,cc.z,cc.w}, p[4]={pp.x,pp.y,pp.z,pp.w};
  float o[4];
  #pragma unroll
  for (int j=0;j<4;j++){
    int d = d4*4 + j;
    float v = fmaf(cw[d*3+0], m[j], fmaf(cw[d*3+1], c[j], fmaf(cw[d*3+2], p[j], cb[d])));
    o[j] = v * sigmoidf_(v);
  }
  *(float4*)&u[(size_t)n*384 + d4*4] = make_float4(o[0],o[1],o[2],o[3]);
}

// ---------------- Kernel 3 (rewritten): tiled dbl = u @ xpw; delta = softplus(dt@dtw+dtb) ----
// 32 tokens/block, 192 threads. u tile + transposed weights staged in LDS (129 KB).
// Each thread: 2 tokens x 4 cols register tile -> 6 ds_read_b128 per 32 FMA.
__global__ __launch_bounds__(192) void k3_xproj(
    const float* __restrict__ u, const float* __restrict__ xpw,
    const float* __restrict__ dtw, const float* __restrict__ dtb,
    float* __restrict__ delta, float* __restrict__ Bc, float* __restrict__ Cc)
{
  __shared__ float su[32][385];    // 49.3 KB  (pad 385: bank-spread)
  __shared__ float wT[48][385];    // 73.9 KB  (cols padded 44->48, zeros)
  __shared__ float sdbl[32][48];   //  6.1 KB
  const int tid = threadIdx.x;
  const int n0 = blockIdx.x * 32;

  for (int i = tid; i < 32*384; i += 192)
    su[i/384][i%384] = u[(size_t)n0*384 + i];
  for (int i = tid; i < 384*48; i += 192) {
    int k = i / 48, j = i % 48;
    wT[j][k] = (j < 44) ? xpw[k*44 + j] : 0.f;
  }
  __syncthreads();

  // phase A: dbl[t][c] for 2 tokens x 4 cols per thread
  const int tg = tid / 12, jg = tid % 12;    // 16 token-groups x 12 col-groups
  const int t0 = tg*2, c0 = jg*4;
  float acc00=0.f, acc01=0.f, acc02=0.f, acc03=0.f;
  float acc10=0.f, acc11=0.f, acc12=0.f, acc13=0.f;
  for (int k = 0; k < 384; k += 4) {
    float4 a0 = *(const float4*)&su[t0  ][k];
    float4 a1 = *(const float4*)&su[t0+1][k];
    float4 w0 = *(const float4*)&wT[c0+0][k];
    float4 w1 = *(const float4*)&wT[c0+1][k];
    float4 w2 = *(const float4*)&wT[c0+2][k];
    float4 w3 = *(const float4*)&wT[c0+3][k];
    acc00 = fmaf(a0.x,w0.x, fmaf(a0.y,w0.y, fmaf(a0.z,w0.z, fmaf(a0.w,w0.w, acc00))));
    acc01 = fmaf(a0.x,w1.x, fmaf(a0.y,w1.y, fmaf(a0.z,w1.z, fmaf(a0.w,w1.w, acc01))));
    acc02 = fmaf(a0.x,w2.x, fmaf(a0.y,w2.y, fmaf(a0.z,w2.z, fmaf(a0.w,w2.w, acc02))));
    acc03 = fmaf(a0.x,w3.x, fmaf(a0.y,w3.y, fmaf(a0.z,w3.z, fmaf(a0.w,w3.w, acc03))));
    acc10 = fmaf(a1.x,w0.x, fmaf(a1.y,w0.y, fmaf(a1.z,w0.z, fmaf(a1.w,w0.w, acc10))));
    acc11 = fmaf(a1.x,w1.x, fmaf(a1.y,w1.y, fmaf(a1.z,w1.z, fmaf(a1.w,w1.w, acc11))));
    acc12 = fmaf(a1.x,w2.x, fmaf(a1.y,w2.y, fmaf(a1.z,w2.z, fmaf(a1.w,w2.w, acc12))));
    acc13 = fmaf(a1.x,w3.x, fmaf(a1.y,w3.y, fmaf(a1.z,w3.z, fmaf(a1.w,w3.w, acc13))));
  }
  sdbl[t0  ][c0+0]=acc00; sdbl[t0  ][c0+1]=acc01; sdbl[t0  ][c0+2]=acc02; sdbl[t0  ][c0+3]=acc03;
  sdbl[t0+1][c0+0]=acc10; sdbl[t0+1][c0+1]=acc11; sdbl[t0+1][c0+2]=acc12; sdbl[t0+1][c0+3]=acc13;
  __syncthreads();

  // phase B: delta = softplus(dt @ dtw + dtb); thread owns channels tid, tid+192
  float wr0[12], wr1[12];
  #pragma unroll
  for (int r = 0; r < 12; r++) { wr0[r] = dtw[r*384 + tid]; wr1[r] = dtw[r*384 + tid + 192]; }
  const float b0 = dtb[tid], b1 = dtb[tid + 192];
  for (int t = 0; t < 32; t++) {
    float a0 = b0, a1 = b1;
    #pragma unroll
    for (int r = 0; r < 12; r++) { float s = sdbl[t][r]; a0 = fmaf(s, wr0[r], a0); a1 = fmaf(s, wr1[r], a1); }
    float sp0 = fmaxf(a0, 0.f) + log1pf(__expf(-fabsf(a0)));
    float sp1 = fmaxf(a1, 0.f) + log1pf(__expf(-fabsf(a1)));
    delta[(size_t)(n0+t)*384 + tid      ] = sp0;
    delta[(size_t)(n0+t)*384 + tid + 192] = sp1;
  }
  for (int i = tid; i < 32*16; i += 192) {
    int t = i >> 4, s = i & 15;
    Bc[(size_t)(n0+t)*16 + s] = sdbl[t][12+s];
    Cc[(size_t)(n0+t)*16 + s] = sdbl[t][28+s];
  }
}

// ---------------- Kernel 4: scan phase 1 (per-chunk product + partial state) ----------------
__global__ __launch_bounds__(384) void k4_scan1(
    const float* __restrict__ delta, const float* __restrict__ u,
    const float* __restrict__ Bc, const float* __restrict__ Alog,
    float* __restrict__ P, float* __restrict__ he)
{
  __shared__ float sB[CHUNK][16];
  const int tid = threadIdx.x; const int c = blockIdx.x; const int n0 = c*CHUNK;
  for (int i = tid; i < CHUNK*16; i += 384) sB[i>>4][i&15] = Bc[(size_t)n0*16 + i];
  float Ac[16];
  #pragma unroll
  for (int s=0;s<16;s++) Ac[s] = -__expf(Alog[tid*16+s]);
  __syncthreads();
  float h[16], Pm[16];
  #pragma unroll
  for (int s=0;s<16;s++){ h[s]=0.f; Pm[s]=1.f; }
  for (int nn=0; nn<CHUNK; nn++){
    size_t n = n0 + nn;
    float dl = delta[n*384 + tid];
    float du = dl * u[n*384 + tid];
    #pragma unroll
    for (int s=0;s<16;s++){
      float a = __expf(dl * Ac[s]);
      h[s] = fmaf(a, h[s], du * sB[nn][s]);
      Pm[s] *= a;
    }
  }
  size_t base = (size_t)c*6144 + (size_t)tid*16;
  #pragma unroll
  for (int s=0;s<16;s+=4){
    *(float4*)&P [base+s] = make_float4(Pm[s],Pm[s+1],Pm[s+2],Pm[s+3]);
    *(float4*)&he[base+s] = make_float4(h[s], h[s+1], h[s+2], h[s+3]);
  }
}

// ---------------- Kernel 5: scan phase 2 (cross-chunk prefix, sw-pipelined) ----------------
__global__ __launch_bounds__(256) void k5_scan2(
    const float* __restrict__ P, const float* __restrict__ he, float* __restrict__ hi)
{
  const int idx = blockIdx.x*256 + threadIdx.x;   // 0..6143
  float H = 0.f;
  float pA[8], eA[8], pB[8], eB[8];
  #pragma unroll
  for (int i = 0; i < 8; i++) {
    size_t o = (size_t)i*6144 + idx; pA[i] = P[o]; eA[i] = he[o];
  }
  for (int c0 = 0; c0 < NCHUNK; c0 += 16) {
    #pragma unroll
    for (int i = 0; i < 8; i++) {
      size_t o = (size_t)(c0+8+i)*6144 + idx; pB[i] = P[o]; eB[i] = he[o];
    }
    #pragma unroll
    for (int i = 0; i < 8; i++) {
      size_t o = (size_t)(c0+i)*6144 + idx; hi[o] = H; H = fmaf(pA[i], H, eA[i]);
    }
    if (c0 + 16 < NCHUNK) {
      #pragma unroll
      for (int i = 0; i < 8; i++) {
        size_t o = (size_t)(c0+16+i)*6144 + idx; pA[i] = P[o]; eA[i] = he[o];
      }
    }
    #pragma unroll
    for (int i = 0; i < 8; i++) {
      size_t o = (size_t)(c0+8+i)*6144 + idx; hi[o] = H; H = fmaf(pB[i], H, eB[i]);
    }
  }
}

// ---------------- Kernel 6: scan phase 3 (re-scan with correct init, emit y) ----------------
__global__ __launch_bounds__(384) void k6_scan3(
    const float* __restrict__ delta, const float* __restrict__ u,
    const float* __restrict__ Bc, const float* __restrict__ Cc,
    const float* __restrict__ Alog, const float* __restrict__ Dp,
    const float* __restrict__ hi, float* __restrict__ y)
{
  __shared__ float sB[CHUNK][16], sC[CHUNK][16];
  const int tid = threadIdx.x; const int c = blockIdx.x; const int n0 = c*CHUNK;
  for (int i = tid; i < CHUNK*16; i += 384){
    sB[i>>4][i&15] = Bc[(size_t)n0*16 + i];
    sC[i>>4][i&15] = Cc[(size_t)n0*16 + i];
  }
  float Ac[16];
  #pragma unroll
  for (int s=0;s<16;s++) Ac[s] = -__expf(Alog[tid*16+s]);
  float h[16];
  size_t base = (size_t)c*6144 + (size_t)tid*16;
  #pragma unroll
  for (int s=0;s<16;s+=4){
    float4 hv = *(const float4*)&hi[base+s];
    h[s]=hv.x; h[s+1]=hv.y; h[s+2]=hv.z; h[s+3]=hv.w;
  }
  float Dpd = Dp[tid];
  __syncthreads();
  for (int nn=0; nn<CHUNK; nn++){
    size_t n = n0 + nn;
    float dl = delta[n*384 + tid];
    float uu = u[n*384 + tid];
    float du = dl * uu;
    float acc = uu * Dpd;
    #pragma unroll
    for (int s=0;s<16;s++){
      float a = __expf(dl * Ac[s]);
      h[s] = fmaf(a, h[s], du * sB[nn][s]);
      acc = fmaf(h[s], sC[nn][s], acc);
    }
    y[n*384 + tid] = acc;
  }
}

// ---------------- Kernel 7: LayerNorm(y) * silu(z) -> g ----------------
__global__ __launch_bounds__(384) void k7_lngate(
    const float* __restrict__ y, const float* __restrict__ z,
    const float* __restrict__ lnw, const float* __restrict__ lnb,
    float* __restrict__ g)
{
  const int tid = threadIdx.x; const size_t n = blockIdx.x;
  float yv = y[n*384 + tid], zv = z[n*384 + tid];
  float s = yv, s2 = yv*yv;
  #pragma unroll
  for (int off = 32; off > 0; off >>= 1){
    s  += __shfl_xor(s,  off);
    s2 += __shfl_xor(s2, off);
  }
  __shared__ float wsum[6], wsum2[6];
  __shared__ float smu, srs;
  int w = tid >> 6;
  if ((tid & 63) == 0){ wsum[w] = s; wsum2[w] = s2; }
  __syncthreads();
  if (tid == 0){
    float S=0.f, S2=0.f;
    #pragma unroll
    for (int i=0;i<6;i++){ S += wsum[i]; S2 += wsum2[i]; }
    float m = S * (1.f/384.f);
    float v = S2 * (1.f/384.f) - m*m;
    smu = m; srs = rsqrtf(v + 1e-5f);
  }
  __syncthreads();
  float ly = (yv - smu)*srs*lnw[tid] + lnb[tid];
  g[n*384 + tid] = ly * zv * sigmoidf_(zv);
}

// ---------------- Kernel 8: out = g @ W_out + x ----------------
__global__ __launch_bounds__(192) void k8_gemm2(
    const float* __restrict__ g, const float* __restrict__ Wout,
    const float* __restrict__ x, float* __restrict__ out)
{
  __shared__ float sg[8][384];
  const int tid = threadIdx.x; const int tok0 = blockIdx.x*8;
  for (int i = tid; i < 8*384; i += 192) sg[i/384][i%384] = g[(size_t)tok0*384 + i];
  __syncthreads();
  float acc[8] = {0.f,0.f,0.f,0.f,0.f,0.f,0.f,0.f};
  for (int k4 = 0; k4 < 96; k4++){
    const int k = k4*4;
    float w0 = Wout[(size_t)(k+0)*192 + tid];
    float w1 = Wout[(size_t)(k+1)*192 + tid];
    float w2 = Wout[(size_t)(k+2)*192 + tid];
    float w3 = Wout[(size_t)(k+3)*192 + tid];
    #pragma unroll
    for (int t=0;t<8;t++){
      float4 gv = *(const float4*)&sg[t][k];
      acc[t] = fmaf(gv.x,w0, fmaf(gv.y,w1, fmaf(gv.z,w2, fmaf(gv.w,w3, acc[t]))));
    }
  }
  #pragma unroll
  for (int t=0;t<8;t++){
    size_t n = tok0 + t;
    out[n*192 + tid] = acc[t] + x[n*192 + tid];
  }
}

extern "C" void kernel_launch(void* const* d_in, const int* in_sizes, int n_in,
                              void* d_out, int out_size, void* d_ws, size_t ws_size,
                              hipStream_t stream) {
  const float* x      = (const float*)d_in[0];
  const float* ln_in_w= (const float*)d_in[1];
  const float* ln_in_b= (const float*)d_in[2];
  const float* W_in   = (const float*)d_in[3];
  const float* conv_w = (const float*)d_in[4];
  const float* conv_b = (const float*)d_in[5];
  const float* xpw    = (const float*)d_in[6];
  const float* dt_w   = (const float*)d_in[7];
  const float* dt_b   = (const float*)d_in[8];
  const float* A_log  = (const float*)d_in[9];
  const float* Dp     = (const float*)d_in[10];
  const float* ln_o_w = (const float*)d_in[11];
  const float* ln_o_b = (const float*)d_in[12];
  const float* W_out  = (const float*)d_in[13];
  float* out = (float*)d_out;

  float* ws = (float*)d_ws;
  const size_t NDI = (size_t)N_TOK * DI;       // 5,308,416
  float* xs   = ws;                 // N x 384   (reused as y by k6)
  float* z    = xs + NDI;           // N x 384
  float* u    = z  + NDI;           // N x 384   (reused as g by k7)
  float* dl   = u  + NDI;           // N x 384
  float* Bc   = dl + NDI;           // N x 16
  float* Cc   = Bc + (size_t)N_TOK*DS;
  float* P    = Cc + (size_t)N_TOK*DS;          // NCHUNK x 6144
  float* he   = P  + (size_t)NCHUNK*DI*DS;
  float* hi   = he + (size_t)NCHUNK*DI*DS;

  k1_ln_gemm1<<<N_TOK/8, 256, 0, stream>>>(x, ln_in_w, ln_in_b, W_in, xs, z);
  k2_conv_silu<<<(N_TOK*96)/256, 256, 0, stream>>>(xs, conv_w, conv_b, u);
  k3_xproj<<<N_TOK/32, 192, 0, stream>>>(u, xpw, dt_w, dt_b, dl, Bc, Cc);
  k4_scan1<<<NCHUNK, 384, 0, stream>>>(dl, u, Bc, A_log, P, he);
  k5_scan2<<<24, 256, 0, stream>>>(P, he, hi);
  k6_scan3<<<NCHUNK, 384, 0, stream>>>(dl, u, Bc, Cc, A_log, Dp, hi, xs /*y*/);
  k7_lngate<<<N_TOK, 384, 0, stream>>>(xs /*y*/, z, ln_o_w, ln_o_b, u /*g*/);
  k8_gemm2<<<N_TOK/8, 192, 0, stream>>>(u /*g*/, W_out, x, out);
}

// Round 3
// 297.540 us; speedup vs baseline: 1.3939x; 1.2062x over previous
//
#include <hip/hip_runtime.h>
#include <math.h>

#define N_TOK 13824
#define DM 192
#define DI 384
#define DS 16
#define DTR 12
#define CHUNK 32
#define NCHUNK 432   // 13824 / 32

__device__ __forceinline__ float sigmoidf_(float x){ return 1.f/(1.f+__expf(-x)); }

// ---------------- Kernel 1: LayerNorm(x) @ W_in -> xs, z ----------------
__global__ __launch_bounds__(256) void k1_ln_gemm1(
    const float* __restrict__ x, const float* __restrict__ lnw,
    const float* __restrict__ lnb, const float* __restrict__ Win,
    float* __restrict__ xs, float* __restrict__ z)
{
  __shared__ float lx[8][192];
  __shared__ float mu[8], rs[8];
  const int tid = threadIdx.x;
  const int tok0 = blockIdx.x * 8;
  for (int i = tid; i < 8*192; i += 256)
    lx[i/192][i%192] = x[(size_t)tok0*192 + i];
  __syncthreads();
  {
    int g = tid >> 5, l = tid & 31;
    float s = 0.f, s2 = 0.f;
    for (int k = l; k < 192; k += 32) { float v = lx[g][k]; s += v; s2 += v*v; }
    #pragma unroll
    for (int off = 16; off > 0; off >>= 1) {
      s  += __shfl_down(s,  off, 32);
      s2 += __shfl_down(s2, off, 32);
    }
    if (l == 0) {
      float m = s * (1.f/192.f);
      float v = s2 * (1.f/192.f) - m*m;
      mu[g] = m; rs[g] = rsqrtf(v + 1e-5f);
    }
  }
  __syncthreads();
  for (int i = tid; i < 8*192; i += 256) {
    int t = i/192, k = i%192;
    lx[t][k] = (lx[t][k]-mu[t])*rs[t]*lnw[k] + lnb[k];
  }
  __syncthreads();

  float acc[8][3];
  #pragma unroll
  for (int t=0;t<8;t++){acc[t][0]=0.f;acc[t][1]=0.f;acc[t][2]=0.f;}
  for (int k4 = 0; k4 < 48; k4++) {
    const int k = k4*4;
    float wv[4][3];
    #pragma unroll
    for (int kk=0;kk<4;kk++){
      wv[kk][0]=Win[(size_t)(k+kk)*768 + tid      ];
      wv[kk][1]=Win[(size_t)(k+kk)*768 + tid + 256];
      wv[kk][2]=Win[(size_t)(k+kk)*768 + tid + 512];
    }
    #pragma unroll
    for (int t=0;t<8;t++){
      float4 lv = *(const float4*)&lx[t][k];
      #pragma unroll
      for (int j=0;j<3;j++)
        acc[t][j] = fmaf(lv.x,wv[0][j], fmaf(lv.y,wv[1][j], fmaf(lv.z,wv[2][j], fmaf(lv.w,wv[3][j], acc[t][j]))));
    }
  }
  #pragma unroll
  for (int t=0;t<8;t++){
    size_t n = tok0 + t;
    xs[n*384 + tid] = acc[t][0];
    int c1 = tid + 256;
    if (c1 < 384) xs[n*384 + c1] = acc[t][1];
    else          z [n*384 + c1-384] = acc[t][1];
    z[n*384 + tid + 128] = acc[t][2];
  }
}

// ---------------- Kernel 2: depthwise conv3 over N + SiLU -> u ----------------
__global__ __launch_bounds__(256) void k2_conv_silu(
    const float* __restrict__ xs, const float* __restrict__ cw,
    const float* __restrict__ cb, float* __restrict__ u)
{
  const int idx = blockIdx.x*256 + threadIdx.x;   // 0 .. N_TOK*96-1
  const int d4 = idx % 96;
  const int n  = idx / 96;
  const float4* x4 = (const float4*)xs;
  float4 cc = x4[(size_t)n*96 + d4];
  float4 mm = make_float4(0.f,0.f,0.f,0.f), pp = make_float4(0.f,0.f,0.f,0.f);
  if (n > 0)         mm = x4[(size_t)(n-1)*96 + d4];
  if (n < N_TOK-1)   pp = x4[(size_t)(n+1)*96 + d4];
  float m[4]={mm.x,mm.y,mm.z,mm.w}, c[4]={cc.x,cc.y,cc.z,cc.w}, p[4]={pp.x,pp.y,pp.z,pp.w};
  float o[4];
  #pragma unroll
  for (int j=0;j<4;j++){
    int d = d4*4 + j;
    float v = fmaf(cw[d*3+0], m[j], fmaf(cw[d*3+1], c[j], fmaf(cw[d*3+2], p[j], cb[d])));
    o[j] = v * sigmoidf_(v);
  }
  *(float4*)&u[(size_t)n*384 + d4*4] = make_float4(o[0],o[1],o[2],o[3]);
}

// ---------------- Kernel 3 (rewritten v2): high-occupancy tiled x_proj + dt_proj ----
// 16 tokens/block, 192 threads = 2 token-groups x 12 col-groups x 8 k-groups.
// Weights stream from L2 (float4 loads), u tile in 25 KB LDS, k-interleaved so
// the 8 kg lanes hit 8 distinct bank-quads (conflict-free ds_read_b128).
__global__ __launch_bounds__(192) void k3_xproj(
    const float* __restrict__ u, const float* __restrict__ xpw,
    const float* __restrict__ dtw, const float* __restrict__ dtb,
    float* __restrict__ delta, float* __restrict__ Bc, float* __restrict__ Cc)
{
  __shared__ float su[16][388];    // 24.8 KB (row stride 388 floats, 16B aligned)
  __shared__ float sdbl[16][48];   //  3.0 KB
  const int tid = threadIdx.x;
  const int n0 = blockIdx.x * 16;

  // stage u tile, float4 coalesced
  for (int i = tid; i < 16*96; i += 192) {
    int t = i / 96, c4 = i % 96;
    *(float4*)&su[t][c4*4] = *(const float4*)(u + (size_t)(n0+t)*384 + c4*4);
  }
  __syncthreads();

  const int tg  = tid / 96;        // 0..1 -> tokens tg*8 .. +7
  const int rem = tid % 96;
  const int jg  = rem >> 3;        // 0..11 (jg==11 idle: cols 44..47 don't exist)
  const int kg  = rem & 7;         // 0..7, k-slice interleaved by float4 blocks
  const int t0  = tg * 8;

  float4 acc[8];
  #pragma unroll
  for (int t = 0; t < 8; t++) acc[t] = make_float4(0.f,0.f,0.f,0.f);

  if (jg < 11) {
    const float* wp = xpw + jg*4;
    for (int m = 0; m < 12; m++) {
      const int k = (m*8 + kg) * 4;          // this thread's float4-block of k
      float4 w0 = *(const float4*)(wp + (size_t)(k+0)*44);
      float4 w1 = *(const float4*)(wp + (size_t)(k+1)*44);
      float4 w2 = *(const float4*)(wp + (size_t)(k+2)*44);
      float4 w3 = *(const float4*)(wp + (size_t)(k+3)*44);
      #pragma unroll
      for (int t = 0; t < 8; t++) {
        float4 a = *(const float4*)&su[t0+t][k];
        acc[t].x = fmaf(a.x,w0.x, fmaf(a.y,w1.x, fmaf(a.z,w2.x, fmaf(a.w,w3.x, acc[t].x))));
        acc[t].y = fmaf(a.x,w0.y, fmaf(a.y,w1.y, fmaf(a.z,w2.y, fmaf(a.w,w3.y, acc[t].y))));
        acc[t].z = fmaf(a.x,w0.z, fmaf(a.y,w1.z, fmaf(a.z,w2.z, fmaf(a.w,w3.z, acc[t].z))));
        acc[t].w = fmaf(a.x,w0.w, fmaf(a.y,w1.w, fmaf(a.z,w2.w, fmaf(a.w,w3.w, acc[t].w))));
      }
    }
  }
  // reduce partial sums across the 8 kg lanes (width-8 butterfly groups)
  #pragma unroll
  for (int t = 0; t < 8; t++) {
    #pragma unroll
    for (int off = 4; off > 0; off >>= 1) {
      acc[t].x += __shfl_down(acc[t].x, off, 8);
      acc[t].y += __shfl_down(acc[t].y, off, 8);
      acc[t].z += __shfl_down(acc[t].z, off, 8);
      acc[t].w += __shfl_down(acc[t].w, off, 8);
    }
  }
  if (kg == 0 && jg < 11) {
    #pragma unroll
    for (int t = 0; t < 8; t++)
      *(float4*)&sdbl[t0+t][jg*4] = acc[t];
  }
  __syncthreads();

  // phase B: delta = softplus(dt @ dtw + dtb); thread owns channels tid, tid+192
  float wr0[12], wr1[12];
  #pragma unroll
  for (int r = 0; r < 12; r++) { wr0[r] = dtw[r*384 + tid]; wr1[r] = dtw[r*384 + tid + 192]; }
  const float b0 = dtb[tid], b1 = dtb[tid + 192];
  for (int t = 0; t < 16; t++) {
    float a0 = b0, a1 = b1;
    #pragma unroll
    for (int r = 0; r < 12; r++) { float s = sdbl[t][r]; a0 = fmaf(s, wr0[r], a0); a1 = fmaf(s, wr1[r], a1); }
    float sp0 = fmaxf(a0, 0.f) + log1pf(__expf(-fabsf(a0)));
    float sp1 = fmaxf(a1, 0.f) + log1pf(__expf(-fabsf(a1)));
    delta[(size_t)(n0+t)*384 + tid      ] = sp0;
    delta[(size_t)(n0+t)*384 + tid + 192] = sp1;
  }
  for (int i = tid; i < 16*16; i += 192) {
    int t = i >> 4, s = i & 15;
    Bc[(size_t)(n0+t)*16 + s] = sdbl[t][12+s];
    Cc[(size_t)(n0+t)*16 + s] = sdbl[t][28+s];
  }
}

// ---------------- Kernel 4: scan phase 1 (per-chunk product + partial state) ----------------
__global__ __launch_bounds__(384) void k4_scan1(
    const float* __restrict__ delta, const float* __restrict__ u,
    const float* __restrict__ Bc, const float* __restrict__ Alog,
    float* __restrict__ P, float* __restrict__ he)
{
  __shared__ float sB[CHUNK][16];
  const int tid = threadIdx.x; const int c = blockIdx.x; const int n0 = c*CHUNK;
  for (int i = tid; i < CHUNK*16; i += 384) sB[i>>4][i&15] = Bc[(size_t)n0*16 + i];
  float Ac[16];
  #pragma unroll
  for (int s=0;s<16;s++) Ac[s] = -__expf(Alog[tid*16+s]);
  __syncthreads();
  float h[16], Pm[16];
  #pragma unroll
  for (int s=0;s<16;s++){ h[s]=0.f; Pm[s]=1.f; }
  for (int nn=0; nn<CHUNK; nn++){
    size_t n = n0 + nn;
    float dl = delta[n*384 + tid];
    float du = dl * u[n*384 + tid];
    #pragma unroll
    for (int s=0;s<16;s++){
      float a = __expf(dl * Ac[s]);
      h[s] = fmaf(a, h[s], du * sB[nn][s]);
      Pm[s] *= a;
    }
  }
  size_t base = (size_t)c*6144 + (size_t)tid*16;
  #pragma unroll
  for (int s=0;s<16;s+=4){
    *(float4*)&P [base+s] = make_float4(Pm[s],Pm[s+1],Pm[s+2],Pm[s+3]);
    *(float4*)&he[base+s] = make_float4(h[s], h[s+1], h[s+2], h[s+3]);
  }
}

// ---------------- Kernel 5: scan phase 2 (cross-chunk prefix, sw-pipelined) ----------------
__global__ __launch_bounds__(256) void k5_scan2(
    const float* __restrict__ P, const float* __restrict__ he, float* __restrict__ hi)
{
  const int idx = blockIdx.x*256 + threadIdx.x;   // 0..6143
  float H = 0.f;
  float pA[8], eA[8], pB[8], eB[8];
  #pragma unroll
  for (int i = 0; i < 8; i++) {
    size_t o = (size_t)i*6144 + idx; pA[i] = P[o]; eA[i] = he[o];
  }
  for (int c0 = 0; c0 < NCHUNK; c0 += 16) {
    #pragma unroll
    for (int i = 0; i < 8; i++) {
      size_t o = (size_t)(c0+8+i)*6144 + idx; pB[i] = P[o]; eB[i] = he[o];
    }
    #pragma unroll
    for (int i = 0; i < 8; i++) {
      size_t o = (size_t)(c0+i)*6144 + idx; hi[o] = H; H = fmaf(pA[i], H, eA[i]);
    }
    if (c0 + 16 < NCHUNK) {
      #pragma unroll
      for (int i = 0; i < 8; i++) {
        size_t o = (size_t)(c0+16+i)*6144 + idx; pA[i] = P[o]; eA[i] = he[o];
      }
    }
    #pragma unroll
    for (int i = 0; i < 8; i++) {
      size_t o = (size_t)(c0+8+i)*6144 + idx; hi[o] = H; H = fmaf(pB[i], H, eB[i]);
    }
  }
}

// ---------------- Kernel 6: scan phase 3 (re-scan with correct init, emit y) ----------------
__global__ __launch_bounds__(384) void k6_scan3(
    const float* __restrict__ delta, const float* __restrict__ u,
    const float* __restrict__ Bc, const float* __restrict__ Cc,
    const float* __restrict__ Alog, const float* __restrict__ Dp,
    const float* __restrict__ hi, float* __restrict__ y)
{
  __shared__ float sB[CHUNK][16], sC[CHUNK][16];
  const int tid = threadIdx.x; const int c = blockIdx.x; const int n0 = c*CHUNK;
  for (int i = tid; i < CHUNK*16; i += 384){
    sB[i>>4][i&15] = Bc[(size_t)n0*16 + i];
    sC[i>>4][i&15] = Cc[(size_t)n0*16 + i];
  }
  float Ac[16];
  #pragma unroll
  for (int s=0;s<16;s++) Ac[s] = -__expf(Alog[tid*16+s]);
  float h[16];
  size_t base = (size_t)c*6144 + (size_t)tid*16;
  #pragma unroll
  for (int s=0;s<16;s+=4){
    float4 hv = *(const float4*)&hi[base+s];
    h[s]=hv.x; h[s+1]=hv.y; h[s+2]=hv.z; h[s+3]=hv.w;
  }
  float Dpd = Dp[tid];
  __syncthreads();
  for (int nn=0; nn<CHUNK; nn++){
    size_t n = n0 + nn;
    float dl = delta[n*384 + tid];
    float uu = u[n*384 + tid];
    float du = dl * uu;
    float acc = uu * Dpd;
    #pragma unroll
    for (int s=0;s<16;s++){
      float a = __expf(dl * Ac[s]);
      h[s] = fmaf(a, h[s], du * sB[nn][s]);
      acc = fmaf(h[s], sC[nn][s], acc);
    }
    y[n*384 + tid] = acc;
  }
}

// ---------------- Kernel 7: LayerNorm(y) * silu(z) -> g ----------------
__global__ __launch_bounds__(384) void k7_lngate(
    const float* __restrict__ y, const float* __restrict__ z,
    const float* __restrict__ lnw, const float* __restrict__ lnb,
    float* __restrict__ g)
{
  const int tid = threadIdx.x; const size_t n = blockIdx.x;
  float yv = y[n*384 + tid], zv = z[n*384 + tid];
  float s = yv, s2 = yv*yv;
  #pragma unroll
  for (int off = 32; off > 0; off >>= 1){
    s  += __shfl_xor(s,  off);
    s2 += __shfl_xor(s2, off);
  }
  __shared__ float wsum[6], wsum2[6];
  __shared__ float smu, srs;
  int w = tid >> 6;
  if ((tid & 63) == 0){ wsum[w] = s; wsum2[w] = s2; }
  __syncthreads();
  if (tid == 0){
    float S=0.f, S2=0.f;
    #pragma unroll
    for (int i=0;i<6;i++){ S += wsum[i]; S2 += wsum2[i]; }
    float m = S * (1.f/384.f);
    float v = S2 * (1.f/384.f) - m*m;
    smu = m; srs = rsqrtf(v + 1e-5f);
  }
  __syncthreads();
  float ly = (yv - smu)*srs*lnw[tid] + lnb[tid];
  g[n*384 + tid] = ly * zv * sigmoidf_(zv);
}

// ---------------- Kernel 8: out = g @ W_out + x ----------------
__global__ __launch_bounds__(192) void k8_gemm2(
    const float* __restrict__ g, const float* __restrict__ Wout,
    const float* __restrict__ x, float* __restrict__ out)
{
  __shared__ float sg[8][384];
  const int tid = threadIdx.x; const int tok0 = blockIdx.x*8;
  for (int i = tid; i < 8*384; i += 192) sg[i/384][i%384] = g[(size_t)tok0*384 + i];
  __syncthreads();
  float acc[8] = {0.f,0.f,0.f,0.f,0.f,0.f,0.f,0.f};
  for (int k4 = 0; k4 < 96; k4++){
    const int k = k4*4;
    float w0 = Wout[(size_t)(k+0)*192 + tid];
    float w1 = Wout[(size_t)(k+1)*192 + tid];
    float w2 = Wout[(size_t)(k+2)*192 + tid];
    float w3 = Wout[(size_t)(k+3)*192 + tid];
    #pragma unroll
    for (int t=0;t<8;t++){
      float4 gv = *(const float4*)&sg[t][k];
      acc[t] = fmaf(gv.x,w0, fmaf(gv.y,w1, fmaf(gv.z,w2, fmaf(gv.w,w3, acc[t]))));
    }
  }
  #pragma unroll
  for (int t=0;t<8;t++){
    size_t n = tok0 + t;
    out[n*192 + tid] = acc[t] + x[n*192 + tid];
  }
}

extern "C" void kernel_launch(void* const* d_in, const int* in_sizes, int n_in,
                              void* d_out, int out_size, void* d_ws, size_t ws_size,
                              hipStream_t stream) {
  const float* x      = (const float*)d_in[0];
  const float* ln_in_w= (const float*)d_in[1];
  const float* ln_in_b= (const float*)d_in[2];
  const float* W_in   = (const float*)d_in[3];
  const float* conv_w = (const float*)d_in[4];
  const float* conv_b = (const float*)d_in[5];
  const float* xpw    = (const float*)d_in[6];
  const float* dt_w   = (const float*)d_in[7];
  const float* dt_b   = (const float*)d_in[8];
  const float* A_log  = (const float*)d_in[9];
  const float* Dp     = (const float*)d_in[10];
  const float* ln_o_w = (const float*)d_in[11];
  const float* ln_o_b = (const float*)d_in[12];
  const float* W_out  = (const float*)d_in[13];
  float* out = (float*)d_out;

  float* ws = (float*)d_ws;
  const size_t NDI = (size_t)N_TOK * DI;       // 5,308,416
  float* xs   = ws;                 // N x 384   (reused as y by k6)
  float* z    = xs + NDI;           // N x 384
  float* u    = z  + NDI;           // N x 384   (reused as g by k7)
  float* dl   = u  + NDI;           // N x 384
  float* Bc   = dl + NDI;           // N x 16
  float* Cc   = Bc + (size_t)N_TOK*DS;
  float* P    = Cc + (size_t)N_TOK*DS;          // NCHUNK x 6144
  float* he   = P  + (size_t)NCHUNK*DI*DS;
  float* hi   = he + (size_t)NCHUNK*DI*DS;

  k1_ln_gemm1<<<N_TOK/8, 256, 0, stream>>>(x, ln_in_w, ln_in_b, W_in, xs, z);
  k2_conv_silu<<<(N_TOK*96)/256, 256, 0, stream>>>(xs, conv_w, conv_b, u);
  k3_xproj<<<N_TOK/16, 192, 0, stream>>>(u, xpw, dt_w, dt_b, dl, Bc, Cc);
  k4_scan1<<<NCHUNK, 384, 0, stream>>>(dl, u, Bc, A_log, P, he);
  k5_scan2<<<24, 256, 0, stream>>>(P, he, hi);
  k6_scan3<<<NCHUNK, 384, 0, stream>>>(dl, u, Bc, Cc, A_log, Dp, hi, xs /*y*/);
  k7_lngate<<<N_TOK, 384, 0, stream>>>(xs /*y*/, z, ln_o_w, ln_o_b, u /*g*/);
  k8_gemm2<<<N_TOK/8, 192, 0, stream>>>(u /*g*/, W_out, x, out);
}

// Round 4
// 208.540 us; speedup vs baseline: 1.9887x; 1.4268x over previous
//
#include <hip/hip_runtime.h>
#include <math.h>

#define N_TOK 13824
#define DM 192
#define DI 384
#define DS 16
#define DTR 12
#define CHUNK 32
#define NCHUNK 432   // 13824 / 32

typedef unsigned short u16;
typedef __attribute__((ext_vector_type(8))) short bf16x8;
typedef __attribute__((ext_vector_type(8))) unsigned short u16x8;
typedef __attribute__((ext_vector_type(4))) float f32x4;

__device__ __forceinline__ float sigmoidf_(float x){ return 1.f/(1.f+__expf(-x)); }
__device__ __forceinline__ u16 f2bf(float f){
  union { float f; unsigned u; } c; c.f = f;
  unsigned u = c.u;
  u += 0x7fffu + ((u>>16)&1u);
  return (u16)(u>>16);
}

// ---------------- Kernel 0: convert W_in / W_out to bf16 MFMA B-fragment order ----
// Fragment (nt,kt): lane l, elem i  <-  W[kt*32 + (l>>4)*8 + i][nt*16 + (l&15)]
// stored at frag_base + (fi*64 + l)*8  (16 B per lane, coalesced on load)
__global__ __launch_bounds__(256) void k0_prep(
    const float* __restrict__ Win, const float* __restrict__ Wout,
    u16* __restrict__ winf, u16* __restrict__ woutf)
{
  const int b = blockIdx.x, tid = threadIdx.x;
  if (b < 72) {                       // W_in: 48 nt x 6 kt = 288 frags
    int g = b*256 + tid; int fi = g>>6, lane = g&63;
    int nt = fi/6, kt = fi%6;
    int n = nt*16 + (lane&15);
    int kb = kt*32 + ((lane>>4)<<3);
    u16 v[8];
    #pragma unroll
    for (int i=0;i<8;i++) v[i] = f2bf(Win[(size_t)(kb+i)*768 + n]);
    u16* dst = winf + ((size_t)fi*64 + lane)*8;
    #pragma unroll
    for (int i=0;i<8;i++) dst[i] = v[i];
  } else {                            // W_out: 12 nt x 12 kt = 144 frags
    int g = (b-72)*256 + tid; int fi = g>>6, lane = g&63;
    int nt = fi/12, kt = fi%12;
    int n = nt*16 + (lane&15);
    int kb = kt*32 + ((lane>>4)<<3);
    u16 v[8];
    #pragma unroll
    for (int i=0;i<8;i++) v[i] = f2bf(Wout[(size_t)(kb+i)*192 + n]);
    u16* dst = woutf + ((size_t)fi*64 + lane)*8;
    #pragma unroll
    for (int i=0;i<8;i++) dst[i] = v[i];
  }
}

// ---------------- Kernel 1 (MFMA): LayerNorm(x) @ W_in -> xs, z ----------------
// 32 tokens/block, 256 threads = 4 waves as 2M x 2N. K=192 (6 k-tiles).
__global__ __launch_bounds__(256) void k1_ln_gemm1(
    const float* __restrict__ x, const float* __restrict__ lnw,
    const float* __restrict__ lnb, const u16* __restrict__ winf,
    float* __restrict__ xs, float* __restrict__ z)
{
  __shared__ u16 sA[32][200];        // 12.5 KB, stride 400 B -> 2-way bank alias (free)
  const int tid = threadIdx.x;
  const int tok0 = blockIdx.x * 32;
  const int wid = tid>>6, lane = tid&63;

  // LN phase: each 8-lane group owns one token
  {
    int t = wid*8 + (lane>>3);
    int l8 = lane&7;
    const float* xrow = x + (size_t)(tok0+t)*192 + l8*4;
    float4 v[6]; float s=0.f, s2=0.f;
    #pragma unroll
    for (int j=0;j<6;j++){
      v[j] = *(const float4*)(xrow + j*32);
      s  += v[j].x+v[j].y+v[j].z+v[j].w;
      s2 += v[j].x*v[j].x + v[j].y*v[j].y + v[j].z*v[j].z + v[j].w*v[j].w;
    }
    #pragma unroll
    for (int off=4; off; off>>=1){ s += __shfl_xor(s, off, 8); s2 += __shfl_xor(s2, off, 8); }
    float m = s*(1.f/192.f);
    float rs = rsqrtf(s2*(1.f/192.f) - m*m + 1e-5f);
    #pragma unroll
    for (int j=0;j<6;j++){
      int k = j*32 + l8*4;
      float4 lw = *(const float4*)(lnw+k);
      float4 lb = *(const float4*)(lnb+k);
      sA[t][k+0] = f2bf((v[j].x-m)*rs*lw.x+lb.x);
      sA[t][k+1] = f2bf((v[j].y-m)*rs*lw.y+lb.y);
      sA[t][k+2] = f2bf((v[j].z-m)*rs*lw.z+lb.z);
      sA[t][k+3] = f2bf((v[j].w-m)*rs*lw.w+lb.w);
    }
  }
  __syncthreads();

  const int wm = wid>>1, wn = wid&1;
  bf16x8 a[6];
  #pragma unroll
  for (int kt=0;kt<6;kt++)
    a[kt] = *(const bf16x8*)&sA[wm*16 + (lane&15)][kt*32 + ((lane>>4)<<3)];

  const bf16x8* wf = (const bf16x8*)winf;
  f32x4 acc[24];
  #pragma unroll
  for (int j=0;j<24;j++) acc[j] = (f32x4){0.f,0.f,0.f,0.f};

  #pragma unroll
  for (int j=0;j<24;j++){
    int nt = wn*24 + j;
    const bf16x8* bp = wf + (size_t)nt*6*64 + lane;
    #pragma unroll
    for (int kt=0;kt<6;kt++)
      acc[j] = __builtin_amdgcn_mfma_f32_16x16x32_bf16(a[kt], bp[kt*64], acc[j], 0,0,0);
  }

  // store: D col = lane&15, row = (lane>>4)*4 + r   [m89-verified layout]
  float* dst = (wn==0) ? xs : z;
  const int r0 = tok0 + wm*16 + ((lane>>4)<<2);
  #pragma unroll
  for (int j=0;j<24;j++){
    int c = j*16 + (lane&15);               // 0..383 within dst
    #pragma unroll
    for (int r=0;r<4;r++)
      dst[(size_t)(r0+r)*384 + c] = acc[j][r];
  }
}

// ---------------- Kernel 2: depthwise conv3 over N + SiLU -> u ----------------
__global__ __launch_bounds__(256) void k2_conv_silu(
    const float* __restrict__ xs, const float* __restrict__ cw,
    const float* __restrict__ cb, float* __restrict__ u)
{
  const int idx = blockIdx.x*256 + threadIdx.x;   // 0 .. N_TOK*96-1
  const int d4 = idx % 96;
  const int n  = idx / 96;
  const float4* x4 = (const float4*)xs;
  float4 cc = x4[(size_t)n*96 + d4];
  float4 mm = make_float4(0.f,0.f,0.f,0.f), pp = make_float4(0.f,0.f,0.f,0.f);
  if (n > 0)         mm = x4[(size_t)(n-1)*96 + d4];
  if (n < N_TOK-1)   pp = x4[(size_t)(n+1)*96 + d4];
  float m[4]={mm.x,mm.y,mm.z,mm.w}, c[4]={cc.x,cc.y,cc.z,cc.w}, p[4]={pp.x,pp.y,pp.z,pp.w};
  float o[4];
  #pragma unroll
  for (int j=0;j<4;j++){
    int d = d4*4 + j;
    float v = fmaf(cw[d*3+0], m[j], fmaf(cw[d*3+1], c[j], fmaf(cw[d*3+2], p[j], cb[d])));
    o[j] = v * sigmoidf_(v);
  }
  *(float4*)&u[(size_t)n*384 + d4*4] = make_float4(o[0],o[1],o[2],o[3]);
}

// ---------------- Kernel 3: high-occupancy tiled x_proj + dt_proj ----
__global__ __launch_bounds__(192) void k3_xproj(
    const float* __restrict__ u, const float* __restrict__ xpw,
    const float* __restrict__ dtw, const float* __restrict__ dtb,
    float* __restrict__ delta, float* __restrict__ Bc, float* __restrict__ Cc)
{
  __shared__ float su[16][388];
  __shared__ float sdbl[16][48];
  const int tid = threadIdx.x;
  const int n0 = blockIdx.x * 16;

  for (int i = tid; i < 16*96; i += 192) {
    int t = i / 96, c4 = i % 96;
    *(float4*)&su[t][c4*4] = *(const float4*)(u + (size_t)(n0+t)*384 + c4*4);
  }
  __syncthreads();

  const int tg  = tid / 96;
  const int rem = tid % 96;
  const int jg  = rem >> 3;
  const int kg  = rem & 7;
  const int t0  = tg * 8;

  float4 acc[8];
  #pragma unroll
  for (int t = 0; t < 8; t++) acc[t] = make_float4(0.f,0.f,0.f,0.f);

  if (jg < 11) {
    const float* wp = xpw + jg*4;
    for (int m = 0; m < 12; m++) {
      const int k = (m*8 + kg) * 4;
      float4 w0 = *(const float4*)(wp + (size_t)(k+0)*44);
      float4 w1 = *(const float4*)(wp + (size_t)(k+1)*44);
      float4 w2 = *(const float4*)(wp + (size_t)(k+2)*44);
      float4 w3 = *(const float4*)(wp + (size_t)(k+3)*44);
      #pragma unroll
      for (int t = 0; t < 8; t++) {
        float4 a = *(const float4*)&su[t0+t][k];
        acc[t].x = fmaf(a.x,w0.x, fmaf(a.y,w1.x, fmaf(a.z,w2.x, fmaf(a.w,w3.x, acc[t].x))));
        acc[t].y = fmaf(a.x,w0.y, fmaf(a.y,w1.y, fmaf(a.z,w2.y, fmaf(a.w,w3.y, acc[t].y))));
        acc[t].z = fmaf(a.x,w0.z, fmaf(a.y,w1.z, fmaf(a.z,w2.z, fmaf(a.w,w3.z, acc[t].z))));
        acc[t].w = fmaf(a.x,w0.w, fmaf(a.y,w1.w, fmaf(a.z,w2.w, fmaf(a.w,w3.w, acc[t].w))));
      }
    }
  }
  #pragma unroll
  for (int t = 0; t < 8; t++) {
    #pragma unroll
    for (int off = 4; off > 0; off >>= 1) {
      acc[t].x += __shfl_down(acc[t].x, off, 8);
      acc[t].y += __shfl_down(acc[t].y, off, 8);
      acc[t].z += __shfl_down(acc[t].z, off, 8);
      acc[t].w += __shfl_down(acc[t].w, off, 8);
    }
  }
  if (kg == 0 && jg < 11) {
    #pragma unroll
    for (int t = 0; t < 8; t++)
      *(float4*)&sdbl[t0+t][jg*4] = acc[t];
  }
  __syncthreads();

  float wr0[12], wr1[12];
  #pragma unroll
  for (int r = 0; r < 12; r++) { wr0[r] = dtw[r*384 + tid]; wr1[r] = dtw[r*384 + tid + 192]; }
  const float b0 = dtb[tid], b1 = dtb[tid + 192];
  for (int t = 0; t < 16; t++) {
    float a0 = b0, a1 = b1;
    #pragma unroll
    for (int r = 0; r < 12; r++) { float s = sdbl[t][r]; a0 = fmaf(s, wr0[r], a0); a1 = fmaf(s, wr1[r], a1); }
    float sp0 = fmaxf(a0, 0.f) + log1pf(__expf(-fabsf(a0)));
    float sp1 = fmaxf(a1, 0.f) + log1pf(__expf(-fabsf(a1)));
    delta[(size_t)(n0+t)*384 + tid      ] = sp0;
    delta[(size_t)(n0+t)*384 + tid + 192] = sp1;
  }
  for (int i = tid; i < 16*16; i += 192) {
    int t = i >> 4, s = i & 15;
    Bc[(size_t)(n0+t)*16 + s] = sdbl[t][12+s];
    Cc[(size_t)(n0+t)*16 + s] = sdbl[t][28+s];
  }
}

// ---------------- Kernel 4: scan phase 1 ----------------
__global__ __launch_bounds__(384) void k4_scan1(
    const float* __restrict__ delta, const float* __restrict__ u,
    const float* __restrict__ Bc, const float* __restrict__ Alog,
    float* __restrict__ P, float* __restrict__ he)
{
  __shared__ float sB[CHUNK][16];
  const int tid = threadIdx.x; const int c = blockIdx.x; const int n0 = c*CHUNK;
  for (int i = tid; i < CHUNK*16; i += 384) sB[i>>4][i&15] = Bc[(size_t)n0*16 + i];
  float Ac[16];
  #pragma unroll
  for (int s=0;s<16;s++) Ac[s] = -__expf(Alog[tid*16+s]);
  __syncthreads();
  float h[16], Pm[16];
  #pragma unroll
  for (int s=0;s<16;s++){ h[s]=0.f; Pm[s]=1.f; }
  for (int nn=0; nn<CHUNK; nn++){
    size_t n = n0 + nn;
    float dl = delta[n*384 + tid];
    float du = dl * u[n*384 + tid];
    #pragma unroll
    for (int s=0;s<16;s++){
      float a = __expf(dl * Ac[s]);
      h[s] = fmaf(a, h[s], du * sB[nn][s]);
      Pm[s] *= a;
    }
  }
  size_t base = (size_t)c*6144 + (size_t)tid*16;
  #pragma unroll
  for (int s=0;s<16;s+=4){
    *(float4*)&P [base+s] = make_float4(Pm[s],Pm[s+1],Pm[s+2],Pm[s+3]);
    *(float4*)&he[base+s] = make_float4(h[s], h[s+1], h[s+2], h[s+3]);
  }
}

// ---------------- Kernel 5: scan phase 2 (cross-chunk prefix, sw-pipelined) ----------------
__global__ __launch_bounds__(256) void k5_scan2(
    const float* __restrict__ P, const float* __restrict__ he, float* __restrict__ hi)
{
  const int idx = blockIdx.x*256 + threadIdx.x;   // 0..6143
  float H = 0.f;
  float pA[8], eA[8], pB[8], eB[8];
  #pragma unroll
  for (int i = 0; i < 8; i++) {
    size_t o = (size_t)i*6144 + idx; pA[i] = P[o]; eA[i] = he[o];
  }
  for (int c0 = 0; c0 < NCHUNK; c0 += 16) {
    #pragma unroll
    for (int i = 0; i < 8; i++) {
      size_t o = (size_t)(c0+8+i)*6144 + idx; pB[i] = P[o]; eB[i] = he[o];
    }
    #pragma unroll
    for (int i = 0; i < 8; i++) {
      size_t o = (size_t)(c0+i)*6144 + idx; hi[o] = H; H = fmaf(pA[i], H, eA[i]);
    }
    if (c0 + 16 < NCHUNK) {
      #pragma unroll
      for (int i = 0; i < 8; i++) {
        size_t o = (size_t)(c0+16+i)*6144 + idx; pA[i] = P[o]; eA[i] = he[o];
      }
    }
    #pragma unroll
    for (int i = 0; i < 8; i++) {
      size_t o = (size_t)(c0+8+i)*6144 + idx; hi[o] = H; H = fmaf(pB[i], H, eB[i]);
    }
  }
}

// ---------------- Kernel 6: scan phase 3 ----------------
__global__ __launch_bounds__(384) void k6_scan3(
    const float* __restrict__ delta, const float* __restrict__ u,
    const float* __restrict__ Bc, const float* __restrict__ Cc,
    const float* __restrict__ Alog, const float* __restrict__ Dp,
    const float* __restrict__ hi, float* __restrict__ y)
{
  __shared__ float sB[CHUNK][16], sC[CHUNK][16];
  const int tid = threadIdx.x; const int c = blockIdx.x; const int n0 = c*CHUNK;
  for (int i = tid; i < CHUNK*16; i += 384){
    sB[i>>4][i&15] = Bc[(size_t)n0*16 + i];
    sC[i>>4][i&15] = Cc[(size_t)n0*16 + i];
  }
  float Ac[16];
  #pragma unroll
  for (int s=0;s<16;s++) Ac[s] = -__expf(Alog[tid*16+s]);
  float h[16];
  size_t base = (size_t)c*6144 + (size_t)tid*16;
  #pragma unroll
  for (int s=0;s<16;s+=4){
    float4 hv = *(const float4*)&hi[base+s];
    h[s]=hv.x; h[s+1]=hv.y; h[s+2]=hv.z; h[s+3]=hv.w;
  }
  float Dpd = Dp[tid];
  __syncthreads();
  for (int nn=0; nn<CHUNK; nn++){
    size_t n = n0 + nn;
    float dl = delta[n*384 + tid];
    float uu = u[n*384 + tid];
    float du = dl * uu;
    float acc = uu * Dpd;
    #pragma unroll
    for (int s=0;s<16;s++){
      float a = __expf(dl * Ac[s]);
      h[s] = fmaf(a, h[s], du * sB[nn][s]);
      acc = fmaf(h[s], sC[nn][s], acc);
    }
    y[n*384 + tid] = acc;
  }
}

// ---------------- Kernel 7: LayerNorm(y) * silu(z) -> g (bf16) ----------------
__global__ __launch_bounds__(384) void k7_lngate(
    const float* __restrict__ y, const float* __restrict__ z,
    const float* __restrict__ lnw, const float* __restrict__ lnb,
    u16* __restrict__ g_bf)
{
  const int tid = threadIdx.x; const size_t n = blockIdx.x;
  float yv = y[n*384 + tid], zv = z[n*384 + tid];
  float s = yv, s2 = yv*yv;
  #pragma unroll
  for (int off = 32; off > 0; off >>= 1){
    s  += __shfl_xor(s,  off);
    s2 += __shfl_xor(s2, off);
  }
  __shared__ float wsum[6], wsum2[6];
  __shared__ float smu, srs;
  int w = tid >> 6;
  if ((tid & 63) == 0){ wsum[w] = s; wsum2[w] = s2; }
  __syncthreads();
  if (tid == 0){
    float S=0.f, S2=0.f;
    #pragma unroll
    for (int i=0;i<6;i++){ S += wsum[i]; S2 += wsum2[i]; }
    float m = S * (1.f/384.f);
    float v = S2 * (1.f/384.f) - m*m;
    smu = m; srs = rsqrtf(v + 1e-5f);
  }
  __syncthreads();
  float ly = (yv - smu)*srs*lnw[tid] + lnb[tid];
  g_bf[n*384 + tid] = f2bf(ly * zv * sigmoidf_(zv));
}

// ---------------- Kernel 8 (MFMA): out = g @ W_out + x ----------------
// 32 tokens/block, 4 waves as 2M x 2N (N=192 -> 96/wave). K=384 (12 k-tiles).
__global__ __launch_bounds__(256) void k8_gemm2(
    const u16* __restrict__ g_bf, const u16* __restrict__ woutf,
    const float* __restrict__ x, float* __restrict__ out)
{
  __shared__ u16 sG[32][392];       // 24.5 KB, stride 784 B -> 2-way alias only
  const int tid = threadIdx.x;
  const int tok0 = blockIdx.x*32;
  for (int i = tid; i < 32*48; i += 256){
    int t = i/48, c8 = i%48;
    *(u16x8*)&sG[t][c8*8] = *(const u16x8*)(g_bf + (size_t)(tok0+t)*384 + c8*8);
  }
  __syncthreads();
  const int wid = tid>>6, lane = tid&63;
  const int wm = wid>>1, wn = wid&1;
  bf16x8 a[12];
  #pragma unroll
  for (int kt=0;kt<12;kt++)
    a[kt] = *(const bf16x8*)&sG[wm*16 + (lane&15)][kt*32 + ((lane>>4)<<3)];
  const bf16x8* wf = (const bf16x8*)woutf;
  const int r0 = tok0 + wm*16 + ((lane>>4)<<2);
  #pragma unroll
  for (int j=0;j<6;j++){
    int nt = wn*6 + j;
    f32x4 acc = (f32x4){0.f,0.f,0.f,0.f};
    const bf16x8* bp = wf + (size_t)nt*12*64 + lane;
    #pragma unroll
    for (int kt=0;kt<12;kt++)
      acc = __builtin_amdgcn_mfma_f32_16x16x32_bf16(a[kt], bp[kt*64], acc, 0,0,0);
    int col = nt*16 + (lane&15);
    #pragma unroll
    for (int r=0;r<4;r++){
      size_t o = (size_t)(r0+r)*192 + col;
      out[o] = acc[r] + x[o];
    }
  }
}

extern "C" void kernel_launch(void* const* d_in, const int* in_sizes, int n_in,
                              void* d_out, int out_size, void* d_ws, size_t ws_size,
                              hipStream_t stream) {
  const float* x      = (const float*)d_in[0];
  const float* ln_in_w= (const float*)d_in[1];
  const float* ln_in_b= (const float*)d_in[2];
  const float* W_in   = (const float*)d_in[3];
  const float* conv_w = (const float*)d_in[4];
  const float* conv_b = (const float*)d_in[5];
  const float* xpw    = (const float*)d_in[6];
  const float* dt_w   = (const float*)d_in[7];
  const float* dt_b   = (const float*)d_in[8];
  const float* A_log  = (const float*)d_in[9];
  const float* Dp     = (const float*)d_in[10];
  const float* ln_o_w = (const float*)d_in[11];
  const float* ln_o_b = (const float*)d_in[12];
  const float* W_out  = (const float*)d_in[13];
  float* out = (float*)d_out;

  float* ws = (float*)d_ws;
  const size_t NDI = (size_t)N_TOK * DI;       // 5,308,416
  float* xs   = ws;                 // N x 384   (reused as y by k6)
  float* z    = xs + NDI;           // N x 384
  float* u    = z  + NDI;           // N x 384
  float* dl   = u  + NDI;           // N x 384 (delta; aliased by g_bf after k6)
  float* Bc   = dl + NDI;           // N x 16
  float* Cc   = Bc + (size_t)N_TOK*DS;
  float* P    = Cc + (size_t)N_TOK*DS;          // NCHUNK x 6144 (aliased by winf before k4)
  float* he   = P  + (size_t)NCHUNK*DI*DS;
  float* hi   = he + (size_t)NCHUNK*DI*DS;
  u16*  winf  = (u16*)P;                         // 288 frags x 1 KB = 295 KB (dead once k1 done)
  u16*  woutf = (u16*)(hi + (size_t)NCHUNK*DI*DS); // 144 frags x 1 KB = 147 KB (appended)
  u16*  g_bf  = (u16*)dl;                        // N x 384 bf16 (delta dead after k6)

  k0_prep    <<<108, 256, 0, stream>>>(W_in, W_out, winf, woutf);
  k1_ln_gemm1<<<N_TOK/32, 256, 0, stream>>>(x, ln_in_w, ln_in_b, winf, xs, z);
  k2_conv_silu<<<(N_TOK*96)/256, 256, 0, stream>>>(xs, conv_w, conv_b, u);
  k3_xproj   <<<N_TOK/16, 192, 0, stream>>>(u, xpw, dt_w, dt_b, dl, Bc, Cc);
  k4_scan1   <<<NCHUNK, 384, 0, stream>>>(dl, u, Bc, A_log, P, he);
  k5_scan2   <<<24, 256, 0, stream>>>(P, he, hi);
  k6_scan3   <<<NCHUNK, 384, 0, stream>>>(dl, u, Bc, Cc, A_log, Dp, hi, xs /*y*/);
  k7_lngate  <<<N_TOK, 384, 0, stream>>>(xs /*y*/, z, ln_o_w, ln_o_b, g_bf);
  k8_gemm2   <<<N_TOK/32, 256, 0, stream>>>(g_bf, woutf, x, out);
}

// Round 5
// 200.143 us; speedup vs baseline: 2.0722x; 1.0420x over previous
//
#include <hip/hip_runtime.h>
#include <math.h>

#define N_TOK 13824
#define DM 192
#define DI 384
#define DS 16
#define DTR 12
#define CHUNK 32
#define NCHUNK 432   // 13824 / 32

typedef unsigned short u16;
typedef __attribute__((ext_vector_type(8))) short bf16x8;
typedef __attribute__((ext_vector_type(8))) unsigned short u16x8;
typedef __attribute__((ext_vector_type(4))) float f32x4;

__device__ __forceinline__ float sigmoidf_(float x){ return 1.f/(1.f+__expf(-x)); }
__device__ __forceinline__ u16 f2bf(float f){
  union { float f; unsigned u; } c; c.f = f;
  unsigned u = c.u;
  u += 0x7fffu + ((u>>16)&1u);
  return (u16)(u>>16);
}

// ---------------- Kernel 0: convert W_in / W_out / xpw to bf16 MFMA B-fragment order ----
// Fragment (nt,kt): lane l, elem i  <-  W[kt*32 + (l>>4)*8 + i][nt*16 + (l&15)]
// stored at frag_base + (fi*64 + l)*8  (16 B per lane, coalesced on load)
__global__ __launch_bounds__(256) void k0_prep(
    const float* __restrict__ Win, const float* __restrict__ Wout,
    const float* __restrict__ xpw,
    u16* __restrict__ winf, u16* __restrict__ woutf, u16* __restrict__ xpwf)
{
  const int b = blockIdx.x, tid = threadIdx.x;
  if (b < 72) {                       // W_in: 48 nt x 6 kt = 288 frags
    int g = b*256 + tid; int fi = g>>6, lane = g&63;
    int nt = fi/6, kt = fi%6;
    int n = nt*16 + (lane&15);
    int kb = kt*32 + ((lane>>4)<<3);
    u16 v[8];
    #pragma unroll
    for (int i=0;i<8;i++) v[i] = f2bf(Win[(size_t)(kb+i)*768 + n]);
    u16* dst = winf + ((size_t)fi*64 + lane)*8;
    #pragma unroll
    for (int i=0;i<8;i++) dst[i] = v[i];
  } else if (b < 108) {               // W_out: 12 nt x 12 kt = 144 frags
    int g = (b-72)*256 + tid; int fi = g>>6, lane = g&63;
    int nt = fi/12, kt = fi%12;
    int n = nt*16 + (lane&15);
    int kb = kt*32 + ((lane>>4)<<3);
    u16 v[8];
    #pragma unroll
    for (int i=0;i<8;i++) v[i] = f2bf(Wout[(size_t)(kb+i)*192 + n]);
    u16* dst = woutf + ((size_t)fi*64 + lane)*8;
    #pragma unroll
    for (int i=0;i<8;i++) dst[i] = v[i];
  } else {                            // xpw: 3 nt x 12 kt = 36 frags (cols 44..47 zero)
    int g = (b-108)*256 + tid; int fi = g>>6, lane = g&63;
    if (fi < 36) {
      int nt = fi/12, kt = fi%12;
      int n = nt*16 + (lane&15);
      int kb = kt*32 + ((lane>>4)<<3);
      u16 v[8];
      #pragma unroll
      for (int i=0;i<8;i++) v[i] = (n < 44) ? f2bf(xpw[(size_t)(kb+i)*44 + n]) : (u16)0;
      u16* dst = xpwf + ((size_t)fi*64 + lane)*8;
      #pragma unroll
      for (int i=0;i<8;i++) dst[i] = v[i];
    }
  }
}

// ---------------- Kernel 1 (MFMA): LayerNorm(x) @ W_in -> xs, z ----------------
// 32 tokens/block, 256 threads = 4 waves as 2M x 2N. K=192 (6 k-tiles).
__global__ __launch_bounds__(256) void k1_ln_gemm1(
    const float* __restrict__ x, const float* __restrict__ lnw,
    const float* __restrict__ lnb, const u16* __restrict__ winf,
    float* __restrict__ xs, float* __restrict__ z)
{
  __shared__ u16 sA[32][200];        // 12.5 KB, stride 400 B -> 2-way bank alias (free)
  const int tid = threadIdx.x;
  const int tok0 = blockIdx.x * 32;
  const int wid = tid>>6, lane = tid&63;

  // LN phase: each 8-lane group owns one token
  {
    int t = wid*8 + (lane>>3);
    int l8 = lane&7;
    const float* xrow = x + (size_t)(tok0+t)*192 + l8*4;
    float4 v[6]; float s=0.f, s2=0.f;
    #pragma unroll
    for (int j=0;j<6;j++){
      v[j] = *(const float4*)(xrow + j*32);
      s  += v[j].x+v[j].y+v[j].z+v[j].w;
      s2 += v[j].x*v[j].x + v[j].y*v[j].y + v[j].z*v[j].z + v[j].w*v[j].w;
    }
    #pragma unroll
    for (int off=4; off; off>>=1){ s += __shfl_xor(s, off, 8); s2 += __shfl_xor(s2, off, 8); }
    float m = s*(1.f/192.f);
    float rs = rsqrtf(s2*(1.f/192.f) - m*m + 1e-5f);
    #pragma unroll
    for (int j=0;j<6;j++){
      int k = j*32 + l8*4;
      float4 lw = *(const float4*)(lnw+k);
      float4 lb = *(const float4*)(lnb+k);
      sA[t][k+0] = f2bf((v[j].x-m)*rs*lw.x+lb.x);
      sA[t][k+1] = f2bf((v[j].y-m)*rs*lw.y+lb.y);
      sA[t][k+2] = f2bf((v[j].z-m)*rs*lw.z+lb.z);
      sA[t][k+3] = f2bf((v[j].w-m)*rs*lw.w+lb.w);
    }
  }
  __syncthreads();

  const int wm = wid>>1, wn = wid&1;
  bf16x8 a[6];
  #pragma unroll
  for (int kt=0;kt<6;kt++)
    a[kt] = *(const bf16x8*)&sA[wm*16 + (lane&15)][kt*32 + ((lane>>4)<<3)];

  const bf16x8* wf = (const bf16x8*)winf;
  f32x4 acc[24];
  #pragma unroll
  for (int j=0;j<24;j++) acc[j] = (f32x4){0.f,0.f,0.f,0.f};

  #pragma unroll
  for (int j=0;j<24;j++){
    int nt = wn*24 + j;
    const bf16x8* bp = wf + (size_t)nt*6*64 + lane;
    #pragma unroll
    for (int kt=0;kt<6;kt++)
      acc[j] = __builtin_amdgcn_mfma_f32_16x16x32_bf16(a[kt], bp[kt*64], acc[j], 0,0,0);
  }

  // store: D col = lane&15, row = (lane>>4)*4 + r   [m89-verified layout]
  float* dst = (wn==0) ? xs : z;
  const int r0 = tok0 + wm*16 + ((lane>>4)<<2);
  #pragma unroll
  for (int j=0;j<24;j++){
    int c = j*16 + (lane&15);               // 0..383 within dst
    #pragma unroll
    for (int r=0;r<4;r++)
      dst[(size_t)(r0+r)*384 + c] = acc[j][r];
  }
}

// ---------------- Kernel 2: depthwise conv3 over N + SiLU -> u ----------------
__global__ __launch_bounds__(256) void k2_conv_silu(
    const float* __restrict__ xs, const float* __restrict__ cw,
    const float* __restrict__ cb, float* __restrict__ u)
{
  const int idx = blockIdx.x*256 + threadIdx.x;   // 0 .. N_TOK*96-1
  const int d4 = idx % 96;
  const int n  = idx / 96;
  const float4* x4 = (const float4*)xs;
  float4 cc = x4[(size_t)n*96 + d4];
  float4 mm = make_float4(0.f,0.f,0.f,0.f), pp = make_float4(0.f,0.f,0.f,0.f);
  if (n > 0)         mm = x4[(size_t)(n-1)*96 + d4];
  if (n < N_TOK-1)   pp = x4[(size_t)(n+1)*96 + d4];
  float m[4]={mm.x,mm.y,mm.z,mm.w}, c[4]={cc.x,cc.y,cc.z,cc.w}, p[4]={pp.x,pp.y,pp.z,pp.w};
  float o[4];
  #pragma unroll
  for (int j=0;j<4;j++){
    int d = d4*4 + j;
    float v = fmaf(cw[d*3+0], m[j], fmaf(cw[d*3+1], c[j], fmaf(cw[d*3+2], p[j], cb[d])));
    o[j] = v * sigmoidf_(v);
  }
  *(float4*)&u[(size_t)n*384 + d4*4] = make_float4(o[0],o[1],o[2],o[3]);
}

// ---------------- Kernel 3 (MFMA v3): dbl = u @ xpw; delta = softplus(dt@dtw+dtb) ----
// 32 tokens/block, 256 threads (4 waves). Waves 0-1 do the 2x(16tok x 48col) MFMA;
// all threads do dt_proj + softplus with coalesced writes.
__global__ __launch_bounds__(256) void k3_xproj(
    const float* __restrict__ u, const u16* __restrict__ xpwf,
    const float* __restrict__ dtw, const float* __restrict__ dtb,
    float* __restrict__ delta, float* __restrict__ Bc, float* __restrict__ Cc)
{
  __shared__ u16 sU[32][200];      // 12.5 KB bf16 u-tile (stride 400 B: 2-way alias, free)
  __shared__ float sdbl[32][48];   //  6 KB
  const int tid = threadIdx.x;
  const int n0 = blockIdx.x * 32;

  // stage u -> bf16 LDS
  for (int i = tid; i < 32*96; i += 256) {
    int t = i/96, c4 = (i%96)*4;
    float4 v = *(const float4*)(u + (size_t)(n0+t)*384 + c4);
    sU[t][c4+0]=f2bf(v.x); sU[t][c4+1]=f2bf(v.y);
    sU[t][c4+2]=f2bf(v.z); sU[t][c4+3]=f2bf(v.w);
  }
  __syncthreads();

  const int wid = tid>>6, lane = tid&63;
  if (wid < 2) {
    bf16x8 a[12];
    #pragma unroll
    for (int kt=0;kt<12;kt++)
      a[kt] = *(const bf16x8*)&sU[wid*16 + (lane&15)][kt*32 + ((lane>>4)<<3)];
    const bf16x8* bfr = (const bf16x8*)xpwf;
    const int r0 = wid*16 + ((lane>>4)<<2);
    #pragma unroll
    for (int nt=0;nt<3;nt++){
      f32x4 acc = (f32x4){0.f,0.f,0.f,0.f};
      const bf16x8* bp = bfr + (size_t)nt*12*64 + lane;
      #pragma unroll
      for (int kt=0;kt<12;kt++)
        acc = __builtin_amdgcn_mfma_f32_16x16x32_bf16(a[kt], bp[kt*64], acc, 0,0,0);
      int c = nt*16 + (lane&15);
      #pragma unroll
      for (int r=0;r<4;r++) sdbl[r0+r][c] = acc[r];
    }
  }
  __syncthreads();

  // dt_proj + softplus: thread covers channel tid (all) and 256+tid (tid<128)
  float wrA[12], wrB[12];
  #pragma unroll
  for (int r=0;r<12;r++) wrA[r] = dtw[r*384 + tid];
  float bA = dtb[tid], bB = 0.f;
  const bool two = (tid < 128);
  if (two) {
    #pragma unroll
    for (int r=0;r<12;r++) wrB[r] = dtw[r*384 + 256 + tid];
    bB = dtb[256 + tid];
  }
  for (int t=0;t<32;t++){
    float d0 = sdbl[t][0], d1 = sdbl[t][1], d2 = sdbl[t][2], d3 = sdbl[t][3];
    float d4 = sdbl[t][4], d5 = sdbl[t][5], d6 = sdbl[t][6], d7 = sdbl[t][7];
    float d8 = sdbl[t][8], d9 = sdbl[t][9], d10 = sdbl[t][10], d11 = sdbl[t][11];
    float a0 = bA;
    a0 = fmaf(d0,wrA[0], a0); a0 = fmaf(d1,wrA[1], a0); a0 = fmaf(d2,wrA[2], a0);
    a0 = fmaf(d3,wrA[3], a0); a0 = fmaf(d4,wrA[4], a0); a0 = fmaf(d5,wrA[5], a0);
    a0 = fmaf(d6,wrA[6], a0); a0 = fmaf(d7,wrA[7], a0); a0 = fmaf(d8,wrA[8], a0);
    a0 = fmaf(d9,wrA[9], a0); a0 = fmaf(d10,wrA[10],a0); a0 = fmaf(d11,wrA[11],a0);
    float sp0 = fmaxf(a0,0.f) + log1pf(__expf(-fabsf(a0)));
    delta[(size_t)(n0+t)*384 + tid] = sp0;
    if (two) {
      float a1 = bB;
      a1 = fmaf(d0,wrB[0], a1); a1 = fmaf(d1,wrB[1], a1); a1 = fmaf(d2,wrB[2], a1);
      a1 = fmaf(d3,wrB[3], a1); a1 = fmaf(d4,wrB[4], a1); a1 = fmaf(d5,wrB[5], a1);
      a1 = fmaf(d6,wrB[6], a1); a1 = fmaf(d7,wrB[7], a1); a1 = fmaf(d8,wrB[8], a1);
      a1 = fmaf(d9,wrB[9], a1); a1 = fmaf(d10,wrB[10],a1); a1 = fmaf(d11,wrB[11],a1);
      float sp1 = fmaxf(a1,0.f) + log1pf(__expf(-fabsf(a1)));
      delta[(size_t)(n0+t)*384 + 256 + tid] = sp1;
    }
  }
  for (int i=tid;i<32*16;i+=256){
    int t=i>>4, s=i&15;
    Bc[(size_t)(n0+t)*16+s] = sdbl[t][12+s];
    Cc[(size_t)(n0+t)*16+s] = sdbl[t][28+s];
  }
}

// ---------------- Kernel 4: scan phase 1 ----------------
__global__ __launch_bounds__(384) void k4_scan1(
    const float* __restrict__ delta, const float* __restrict__ u,
    const float* __restrict__ Bc, const float* __restrict__ Alog,
    float* __restrict__ P, float* __restrict__ he)
{
  __shared__ float sB[CHUNK][16];
  const int tid = threadIdx.x; const int c = blockIdx.x; const int n0 = c*CHUNK;
  for (int i = tid; i < CHUNK*16; i += 384) sB[i>>4][i&15] = Bc[(size_t)n0*16 + i];
  float Ac[16];
  #pragma unroll
  for (int s=0;s<16;s++) Ac[s] = -__expf(Alog[tid*16+s]);
  __syncthreads();
  float h[16], Pm[16];
  #pragma unroll
  for (int s=0;s<16;s++){ h[s]=0.f; Pm[s]=1.f; }
  for (int nn=0; nn<CHUNK; nn++){
    size_t n = n0 + nn;
    float dl = delta[n*384 + tid];
    float du = dl * u[n*384 + tid];
    #pragma unroll
    for (int s=0;s<16;s++){
      float a = __expf(dl * Ac[s]);
      h[s] = fmaf(a, h[s], du * sB[nn][s]);
      Pm[s] *= a;
    }
  }
  size_t base = (size_t)c*6144 + (size_t)tid*16;
  #pragma unroll
  for (int s=0;s<16;s+=4){
    *(float4*)&P [base+s] = make_float4(Pm[s],Pm[s+1],Pm[s+2],Pm[s+3]);
    *(float4*)&he[base+s] = make_float4(h[s], h[s+1], h[s+2], h[s+3]);
  }
}

// ---------------- Kernel 5: scan phase 2 (cross-chunk prefix, sw-pipelined) ----------------
__global__ __launch_bounds__(256) void k5_scan2(
    const float* __restrict__ P, const float* __restrict__ he, float* __restrict__ hi)
{
  const int idx = blockIdx.x*256 + threadIdx.x;   // 0..6143
  float H = 0.f;
  float pA[8], eA[8], pB[8], eB[8];
  #pragma unroll
  for (int i = 0; i < 8; i++) {
    size_t o = (size_t)i*6144 + idx; pA[i] = P[o]; eA[i] = he[o];
  }
  for (int c0 = 0; c0 < NCHUNK; c0 += 16) {
    #pragma unroll
    for (int i = 0; i < 8; i++) {
      size_t o = (size_t)(c0+8+i)*6144 + idx; pB[i] = P[o]; eB[i] = he[o];
    }
    #pragma unroll
    for (int i = 0; i < 8; i++) {
      size_t o = (size_t)(c0+i)*6144 + idx; hi[o] = H; H = fmaf(pA[i], H, eA[i]);
    }
    if (c0 + 16 < NCHUNK) {
      #pragma unroll
      for (int i = 0; i < 8; i++) {
        size_t o = (size_t)(c0+16+i)*6144 + idx; pA[i] = P[o]; eA[i] = he[o];
      }
    }
    #pragma unroll
    for (int i = 0; i < 8; i++) {
      size_t o = (size_t)(c0+8+i)*6144 + idx; hi[o] = H; H = fmaf(pB[i], H, eB[i]);
    }
  }
}

// ---------------- Kernel 6: scan phase 3 ----------------
__global__ __launch_bounds__(384) void k6_scan3(
    const float* __restrict__ delta, const float* __restrict__ u,
    const float* __restrict__ Bc, const float* __restrict__ Cc,
    const float* __restrict__ Alog, const float* __restrict__ Dp,
    const float* __restrict__ hi, float* __restrict__ y)
{
  __shared__ float sB[CHUNK][16], sC[CHUNK][16];
  const int tid = threadIdx.x; const int c = blockIdx.x; const int n0 = c*CHUNK;
  for (int i = tid; i < CHUNK*16; i += 384){
    sB[i>>4][i&15] = Bc[(size_t)n0*16 + i];
    sC[i>>4][i&15] = Cc[(size_t)n0*16 + i];
  }
  float Ac[16];
  #pragma unroll
  for (int s=0;s<16;s++) Ac[s] = -__expf(Alog[tid*16+s]);
  float h[16];
  size_t base = (size_t)c*6144 + (size_t)tid*16;
  #pragma unroll
  for (int s=0;s<16;s+=4){
    float4 hv = *(const float4*)&hi[base+s];
    h[s]=hv.x; h[s+1]=hv.y; h[s+2]=hv.z; h[s+3]=hv.w;
  }
  float Dpd = Dp[tid];
  __syncthreads();
  for (int nn=0; nn<CHUNK; nn++){
    size_t n = n0 + nn;
    float dl = delta[n*384 + tid];
    float uu = u[n*384 + tid];
    float du = dl * uu;
    float acc = uu * Dpd;
    #pragma unroll
    for (int s=0;s<16;s++){
      float a = __expf(dl * Ac[s]);
      h[s] = fmaf(a, h[s], du * sB[nn][s]);
      acc = fmaf(h[s], sC[nn][s], acc);
    }
    y[n*384 + tid] = acc;
  }
}

// ---------------- Kernel 7: LayerNorm(y) * silu(z) -> g (bf16) ----------------
__global__ __launch_bounds__(384) void k7_lngate(
    const float* __restrict__ y, const float* __restrict__ z,
    const float* __restrict__ lnw, const float* __restrict__ lnb,
    u16* __restrict__ g_bf)
{
  const int tid = threadIdx.x; const size_t n = blockIdx.x;
  float yv = y[n*384 + tid], zv = z[n*384 + tid];
  float s = yv, s2 = yv*yv;
  #pragma unroll
  for (int off = 32; off > 0; off >>= 1){
    s  += __shfl_xor(s,  off);
    s2 += __shfl_xor(s2, off);
  }
  __shared__ float wsum[6], wsum2[6];
  __shared__ float smu, srs;
  int w = tid >> 6;
  if ((tid & 63) == 0){ wsum[w] = s; wsum2[w] = s2; }
  __syncthreads();
  if (tid == 0){
    float S=0.f, S2=0.f;
    #pragma unroll
    for (int i=0;i<6;i++){ S += wsum[i]; S2 += wsum2[i]; }
    float m = S * (1.f/384.f);
    float v = S2 * (1.f/384.f) - m*m;
    smu = m; srs = rsqrtf(v + 1e-5f);
  }
  __syncthreads();
  float ly = (yv - smu)*srs*lnw[tid] + lnb[tid];
  g_bf[n*384 + tid] = f2bf(ly * zv * sigmoidf_(zv));
}

// ---------------- Kernel 8 (MFMA): out = g @ W_out + x ----------------
__global__ __launch_bounds__(256) void k8_gemm2(
    const u16* __restrict__ g_bf, const u16* __restrict__ woutf,
    const float* __restrict__ x, float* __restrict__ out)
{
  __shared__ u16 sG[32][392];       // 24.5 KB, stride 784 B -> 2-way alias only
  const int tid = threadIdx.x;
  const int tok0 = blockIdx.x*32;
  for (int i = tid; i < 32*48; i += 256){
    int t = i/48, c8 = i%48;
    *(u16x8*)&sG[t][c8*8] = *(const u16x8*)(g_bf + (size_t)(tok0+t)*384 + c8*8);
  }
  __syncthreads();
  const int wid = tid>>6, lane = tid&63;
  const int wm = wid>>1, wn = wid&1;
  bf16x8 a[12];
  #pragma unroll
  for (int kt=0;kt<12;kt++)
    a[kt] = *(const bf16x8*)&sG[wm*16 + (lane&15)][kt*32 + ((lane>>4)<<3)];
  const bf16x8* wf = (const bf16x8*)woutf;
  const int r0 = tok0 + wm*16 + ((lane>>4)<<2);
  #pragma unroll
  for (int j=0;j<6;j++){
    int nt = wn*6 + j;
    f32x4 acc = (f32x4){0.f,0.f,0.f,0.f};
    const bf16x8* bp = wf + (size_t)nt*12*64 + lane;
    #pragma unroll
    for (int kt=0;kt<12;kt++)
      acc = __builtin_amdgcn_mfma_f32_16x16x32_bf16(a[kt], bp[kt*64], acc, 0,0,0);
    int col = nt*16 + (lane&15);
    #pragma unroll
    for (int r=0;r<4;r++){
      size_t o = (size_t)(r0+r)*192 + col;
      out[o] = acc[r] + x[o];
    }
  }
}

extern "C" void kernel_launch(void* const* d_in, const int* in_sizes, int n_in,
                              void* d_out, int out_size, void* d_ws, size_t ws_size,
                              hipStream_t stream) {
  const float* x      = (const float*)d_in[0];
  const float* ln_in_w= (const float*)d_in[1];
  const float* ln_in_b= (const float*)d_in[2];
  const float* W_in   = (const float*)d_in[3];
  const float* conv_w = (const float*)d_in[4];
  const float* conv_b = (const float*)d_in[5];
  const float* xpw    = (const float*)d_in[6];
  const float* dt_w   = (const float*)d_in[7];
  const float* dt_b   = (const float*)d_in[8];
  const float* A_log  = (const float*)d_in[9];
  const float* Dp     = (const float*)d_in[10];
  const float* ln_o_w = (const float*)d_in[11];
  const float* ln_o_b = (const float*)d_in[12];
  const float* W_out  = (const float*)d_in[13];
  float* out = (float*)d_out;

  float* ws = (float*)d_ws;
  const size_t NDI = (size_t)N_TOK * DI;       // 5,308,416
  float* xs   = ws;                 // N x 384   (reused as y by k6)
  float* z    = xs + NDI;           // N x 384
  float* u    = z  + NDI;           // N x 384
  float* dl   = u  + NDI;           // N x 384 (delta; aliased by g_bf after k6)
  float* Bc   = dl + NDI;           // N x 16
  float* Cc   = Bc + (size_t)N_TOK*DS;
  float* P    = Cc + (size_t)N_TOK*DS;          // NCHUNK x 6144 (aliased by winf before k4)
  float* he   = P  + (size_t)NCHUNK*DI*DS;
  float* hi   = he + (size_t)NCHUNK*DI*DS;
  u16*  winf  = (u16*)P;                         // 288 frags x 1 KB (dead once k1 done)
  u16*  woutf = (u16*)(hi + (size_t)NCHUNK*DI*DS); // 144 frags x 1 KB
  u16*  xpwf  = woutf + (size_t)144*512;         // 36 frags x 1 KB
  u16*  g_bf  = (u16*)dl;                        // N x 384 bf16 (delta dead after k6)

  k0_prep    <<<117, 256, 0, stream>>>(W_in, W_out, xpw, winf, woutf, xpwf);
  k1_ln_gemm1<<<N_TOK/32, 256, 0, stream>>>(x, ln_in_w, ln_in_b, winf, xs, z);
  k2_conv_silu<<<(N_TOK*96)/256, 256, 0, stream>>>(xs, conv_w, conv_b, u);
  k3_xproj   <<<N_TOK/32, 256, 0, stream>>>(u, xpwf, dt_w, dt_b, dl, Bc, Cc);
  k4_scan1   <<<NCHUNK, 384, 0, stream>>>(dl, u, Bc, A_log, P, he);
  k5_scan2   <<<24, 256, 0, stream>>>(P, he, hi);
  k6_scan3   <<<NCHUNK, 384, 0, stream>>>(dl, u, Bc, Cc, A_log, Dp, hi, xs /*y*/);
  k7_lngate  <<<N_TOK, 384, 0, stream>>>(xs /*y*/, z, ln_o_w, ln_o_b, g_bf);
  k8_gemm2   <<<N_TOK/32, 256, 0, stream>>>(g_bf, woutf, x, out);
}

// Round 6
// 182.965 us; speedup vs baseline: 2.2667x; 1.0939x over previous
//
#include <hip/hip_runtime.h>
#include <math.h>

#define N_TOK 13824
#define DM 192
#define DI 384
#define DS 16
#define DTR 12
#define CHUNK 32
#define NCHUNK 432   // 13824 / 32

typedef unsigned short u16;
typedef __attribute__((ext_vector_type(8))) short bf16x8;
typedef __attribute__((ext_vector_type(8))) unsigned short u16x8;
typedef __attribute__((ext_vector_type(4))) float f32x4;

__device__ __forceinline__ float sigmoidf_(float x){ return 1.f/(1.f+__expf(-x)); }
__device__ __forceinline__ u16 f2bf(float f){
  union { float f; unsigned u; } c; c.f = f;
  unsigned u = c.u;
  u += 0x7fffu + ((u>>16)&1u);
  return (u16)(u>>16);
}

// ---------------- Kernel 0: convert W_in / W_out / xpw to bf16 MFMA B-fragment order ----
// Fragment (nt,kt): lane l, elem i  <-  W[kt*32 + (l>>4)*8 + i][nt*16 + (l&15)]
__global__ __launch_bounds__(256) void k0_prep(
    const float* __restrict__ Win, const float* __restrict__ Wout,
    const float* __restrict__ xpw,
    u16* __restrict__ winf, u16* __restrict__ woutf, u16* __restrict__ xpwf)
{
  const int b = blockIdx.x, tid = threadIdx.x;
  if (b < 72) {                       // W_in: 48 nt x 6 kt = 288 frags
    int g = b*256 + tid; int fi = g>>6, lane = g&63;
    int nt = fi/6, kt = fi%6;
    int n = nt*16 + (lane&15);
    int kb = kt*32 + ((lane>>4)<<3);
    u16 v[8];
    #pragma unroll
    for (int i=0;i<8;i++) v[i] = f2bf(Win[(size_t)(kb+i)*768 + n]);
    u16* dst = winf + ((size_t)fi*64 + lane)*8;
    #pragma unroll
    for (int i=0;i<8;i++) dst[i] = v[i];
  } else if (b < 108) {               // W_out: 12 nt x 12 kt = 144 frags
    int g = (b-72)*256 + tid; int fi = g>>6, lane = g&63;
    int nt = fi/12, kt = fi%12;
    int n = nt*16 + (lane&15);
    int kb = kt*32 + ((lane>>4)<<3);
    u16 v[8];
    #pragma unroll
    for (int i=0;i<8;i++) v[i] = f2bf(Wout[(size_t)(kb+i)*192 + n]);
    u16* dst = woutf + ((size_t)fi*64 + lane)*8;
    #pragma unroll
    for (int i=0;i<8;i++) dst[i] = v[i];
  } else {                            // xpw: 3 nt x 12 kt = 36 frags (cols 44..47 zero)
    int g = (b-108)*256 + tid; int fi = g>>6, lane = g&63;
    if (fi < 36) {
      int nt = fi/12, kt = fi%12;
      int n = nt*16 + (lane&15);
      int kb = kt*32 + ((lane>>4)<<3);
      u16 v[8];
      #pragma unroll
      for (int i=0;i<8;i++) v[i] = (n < 44) ? f2bf(xpw[(size_t)(kb+i)*44 + n]) : (u16)0;
      u16* dst = xpwf + ((size_t)fi*64 + lane)*8;
      #pragma unroll
      for (int i=0;i<8;i++) dst[i] = v[i];
    }
  }
}

// ---------------- Kernel 1 (MFMA): LayerNorm(x) @ W_in -> xs, z ----------------
__global__ __launch_bounds__(256) void k1_ln_gemm1(
    const float* __restrict__ x, const float* __restrict__ lnw,
    const float* __restrict__ lnb, const u16* __restrict__ winf,
    float* __restrict__ xs, float* __restrict__ z)
{
  __shared__ u16 sA[32][200];        // 12.5 KB, stride 400 B -> 2-way bank alias (free)
  const int tid = threadIdx.x;
  const int tok0 = blockIdx.x * 32;
  const int wid = tid>>6, lane = tid&63;

  {
    int t = wid*8 + (lane>>3);
    int l8 = lane&7;
    const float* xrow = x + (size_t)(tok0+t)*192 + l8*4;
    float4 v[6]; float s=0.f, s2=0.f;
    #pragma unroll
    for (int j=0;j<6;j++){
      v[j] = *(const float4*)(xrow + j*32);
      s  += v[j].x+v[j].y+v[j].z+v[j].w;
      s2 += v[j].x*v[j].x + v[j].y*v[j].y + v[j].z*v[j].z + v[j].w*v[j].w;
    }
    #pragma unroll
    for (int off=4; off; off>>=1){ s += __shfl_xor(s, off, 8); s2 += __shfl_xor(s2, off, 8); }
    float m = s*(1.f/192.f);
    float rs = rsqrtf(s2*(1.f/192.f) - m*m + 1e-5f);
    #pragma unroll
    for (int j=0;j<6;j++){
      int k = j*32 + l8*4;
      float4 lw = *(const float4*)(lnw+k);
      float4 lb = *(const float4*)(lnb+k);
      sA[t][k+0] = f2bf((v[j].x-m)*rs*lw.x+lb.x);
      sA[t][k+1] = f2bf((v[j].y-m)*rs*lw.y+lb.y);
      sA[t][k+2] = f2bf((v[j].z-m)*rs*lw.z+lb.z);
      sA[t][k+3] = f2bf((v[j].w-m)*rs*lw.w+lb.w);
    }
  }
  __syncthreads();

  const int wm = wid>>1, wn = wid&1;
  bf16x8 a[6];
  #pragma unroll
  for (int kt=0;kt<6;kt++)
    a[kt] = *(const bf16x8*)&sA[wm*16 + (lane&15)][kt*32 + ((lane>>4)<<3)];

  const bf16x8* wf = (const bf16x8*)winf;
  f32x4 acc[24];
  #pragma unroll
  for (int j=0;j<24;j++) acc[j] = (f32x4){0.f,0.f,0.f,0.f};

  #pragma unroll
  for (int j=0;j<24;j++){
    int nt = wn*24 + j;
    const bf16x8* bp = wf + (size_t)nt*6*64 + lane;
    #pragma unroll
    for (int kt=0;kt<6;kt++)
      acc[j] = __builtin_amdgcn_mfma_f32_16x16x32_bf16(a[kt], bp[kt*64], acc[j], 0,0,0);
  }

  float* dst = (wn==0) ? xs : z;
  const int r0 = tok0 + wm*16 + ((lane>>4)<<2);
  #pragma unroll
  for (int j=0;j<24;j++){
    int c = j*16 + (lane&15);
    #pragma unroll
    for (int r=0;r<4;r++)
      dst[(size_t)(r0+r)*384 + c] = acc[j][r];
  }
}

// ---------------- Kernel 2: depthwise conv3 over N + SiLU -> u ----------------
__global__ __launch_bounds__(256) void k2_conv_silu(
    const float* __restrict__ xs, const float* __restrict__ cw,
    const float* __restrict__ cb, float* __restrict__ u)
{
  const int idx = blockIdx.x*256 + threadIdx.x;   // 0 .. N_TOK*96-1
  const int d4 = idx % 96;
  const int n  = idx / 96;
  const float4* x4 = (const float4*)xs;
  float4 cc = x4[(size_t)n*96 + d4];
  float4 mm = make_float4(0.f,0.f,0.f,0.f), pp = make_float4(0.f,0.f,0.f,0.f);
  if (n > 0)         mm = x4[(size_t)(n-1)*96 + d4];
  if (n < N_TOK-1)   pp = x4[(size_t)(n+1)*96 + d4];
  float m[4]={mm.x,mm.y,mm.z,mm.w}, c[4]={cc.x,cc.y,cc.z,cc.w}, p[4]={pp.x,pp.y,pp.z,pp.w};
  float o[4];
  #pragma unroll
  for (int j=0;j<4;j++){
    int d = d4*4 + j;
    float v = fmaf(cw[d*3+0], m[j], fmaf(cw[d*3+1], c[j], fmaf(cw[d*3+2], p[j], cb[d])));
    o[j] = v * sigmoidf_(v);
  }
  *(float4*)&u[(size_t)n*384 + d4*4] = make_float4(o[0],o[1],o[2],o[3]);
}

// ---------------- Kernel 34 (fused): x_proj MFMA + dt_proj + scan phase 1 ----------------
// One block per scan chunk (32 tokens), 384 threads (6 waves = 2M x 3N MFMA split).
// u staged fp32 in LDS once; delta computed on the fly; scan runs out of LDS.
__global__ __launch_bounds__(384) void k34_xproj_scan1(
    const float* __restrict__ u, const u16* __restrict__ xpwf,
    const float* __restrict__ dtw, const float* __restrict__ dtb,
    const float* __restrict__ Alog,
    float* __restrict__ delta, float* __restrict__ Bc, float* __restrict__ Cc,
    float* __restrict__ P, float* __restrict__ he)
{
  __shared__ float sU[32][396];    // 50.7 KB (stride 396: rows 12 banks apart -> 2-way max)
  __shared__ float sdbl[32][48];   //  6 KB
  const int tid = threadIdx.x;
  const int c = blockIdx.x; const int n0 = c*CHUNK;

  for (int i = tid; i < 32*96; i += 384) {
    int t = i/96, c4 = (i%96)*4;
    *(float4*)&sU[t][c4] = *(const float4*)(u + (size_t)(n0+t)*384 + c4);
  }
  __syncthreads();

  const int wid = tid>>6, lane = tid&63;
  {
    const int wm = wid & 1, wnt = wid >> 1;    // 2 M-halves x 3 n-tiles
    const int arow = wm*16 + (lane&15);
    f32x4 acc = (f32x4){0.f,0.f,0.f,0.f};
    const bf16x8* bp = (const bf16x8*)xpwf + (size_t)wnt*12*64 + lane;
    #pragma unroll
    for (int kt=0;kt<12;kt++){
      int k0 = kt*32 + ((lane>>4)<<3);
      float4 f0 = *(const float4*)&sU[arow][k0];
      float4 f1 = *(const float4*)&sU[arow][k0+4];
      bf16x8 a;
      a[0]=(short)f2bf(f0.x); a[1]=(short)f2bf(f0.y); a[2]=(short)f2bf(f0.z); a[3]=(short)f2bf(f0.w);
      a[4]=(short)f2bf(f1.x); a[5]=(short)f2bf(f1.y); a[6]=(short)f2bf(f1.z); a[7]=(short)f2bf(f1.w);
      acc = __builtin_amdgcn_mfma_f32_16x16x32_bf16(a, bp[kt*64], acc, 0,0,0);
    }
    int ccol = wnt*16 + (lane&15);
    int r0 = wm*16 + ((lane>>4)<<2);
    #pragma unroll
    for (int r=0;r<4;r++) sdbl[r0+r][ccol] = acc[r];
  }
  __syncthreads();

  // Bc/Cc for k67
  for (int i=tid;i<32*16;i+=384){
    int t=i>>4, s=i&15;
    Bc[(size_t)(n0+t)*16+s] = sdbl[t][12+s];
    Cc[(size_t)(n0+t)*16+s] = sdbl[t][28+s];
  }

  // scan: thread = channel
  float Ac[16];
  #pragma unroll
  for (int s=0;s<16;s++) Ac[s] = -__expf(Alog[tid*16+s]);
  float wr[12];
  #pragma unroll
  for (int r=0;r<12;r++) wr[r] = dtw[r*384 + tid];
  const float bb = dtb[tid];
  float h[16], Pm[16];
  #pragma unroll
  for (int s=0;s<16;s++){ h[s]=0.f; Pm[s]=1.f; }

  for (int t=0;t<32;t++){
    float a0 = bb;
    #pragma unroll
    for (int r=0;r<12;r++) a0 = fmaf(sdbl[t][r], wr[r], a0);
    float dl = fmaxf(a0,0.f) + log1pf(__expf(-fabsf(a0)));
    delta[(size_t)(n0+t)*384 + tid] = dl;
    float du = dl * sU[t][tid];
    #pragma unroll
    for (int s=0;s<16;s++){
      float a = __expf(dl * Ac[s]);
      h[s] = fmaf(a, h[s], du * sdbl[t][12+s]);
      Pm[s] *= a;
    }
  }
  size_t base = (size_t)c*6144 + (size_t)tid*16;
  #pragma unroll
  for (int s=0;s<16;s+=4){
    *(float4*)&P [base+s] = make_float4(Pm[s],Pm[s+1],Pm[s+2],Pm[s+3]);
    *(float4*)&he[base+s] = make_float4(h[s], h[s+1], h[s+2], h[s+3]);
  }
}

// ---------------- Kernel 5: scan phase 2 (cross-chunk prefix, sw-pipelined) ----------------
__global__ __launch_bounds__(256) void k5_scan2(
    const float* __restrict__ P, const float* __restrict__ he, float* __restrict__ hi)
{
  const int idx = blockIdx.x*256 + threadIdx.x;   // 0..6143
  float H = 0.f;
  float pA[8], eA[8], pB[8], eB[8];
  #pragma unroll
  for (int i = 0; i < 8; i++) {
    size_t o = (size_t)i*6144 + idx; pA[i] = P[o]; eA[i] = he[o];
  }
  for (int c0 = 0; c0 < NCHUNK; c0 += 16) {
    #pragma unroll
    for (int i = 0; i < 8; i++) {
      size_t o = (size_t)(c0+8+i)*6144 + idx; pB[i] = P[o]; eB[i] = he[o];
    }
    #pragma unroll
    for (int i = 0; i < 8; i++) {
      size_t o = (size_t)(c0+i)*6144 + idx; hi[o] = H; H = fmaf(pA[i], H, eA[i]);
    }
    if (c0 + 16 < NCHUNK) {
      #pragma unroll
      for (int i = 0; i < 8; i++) {
        size_t o = (size_t)(c0+16+i)*6144 + idx; pA[i] = P[o]; eA[i] = he[o];
      }
    }
    #pragma unroll
    for (int i = 0; i < 8; i++) {
      size_t o = (size_t)(c0+8+i)*6144 + idx; hi[o] = H; H = fmaf(pB[i], H, eB[i]);
    }
  }
}

// ---------------- Kernel 67 (fused): scan phase 3 + LayerNorm(y)*silu(z) -> g_bf ----------------
__global__ __launch_bounds__(384) void k67_scan3_lngate(
    const float* __restrict__ delta, const float* __restrict__ u,
    const float* __restrict__ Bc, const float* __restrict__ Cc,
    const float* __restrict__ Alog, const float* __restrict__ Dp,
    const float* __restrict__ hi, const float* __restrict__ z,
    const float* __restrict__ lnw, const float* __restrict__ lnb,
    u16* __restrict__ g_bf)
{
  __shared__ float sB[CHUNK][16], sC[CHUNK][16];
  __shared__ float sY[32][396];   // 50.7 KB
  const int tid = threadIdx.x; const int c = blockIdx.x; const int n0 = c*CHUNK;
  for (int i = tid; i < CHUNK*16; i += 384){
    sB[i>>4][i&15] = Bc[(size_t)n0*16 + i];
    sC[i>>4][i&15] = Cc[(size_t)n0*16 + i];
  }
  float Ac[16];
  #pragma unroll
  for (int s=0;s<16;s++) Ac[s] = -__expf(Alog[tid*16+s]);
  float h[16];
  size_t base = (size_t)c*6144 + (size_t)tid*16;
  #pragma unroll
  for (int s=0;s<16;s+=4){
    float4 hv = *(const float4*)&hi[base+s];
    h[s]=hv.x; h[s+1]=hv.y; h[s+2]=hv.z; h[s+3]=hv.w;
  }
  float Dpd = Dp[tid];
  __syncthreads();
  for (int nn=0; nn<CHUNK; nn++){
    size_t n = n0 + nn;
    float dl = delta[n*384 + tid];
    float uu = u[n*384 + tid];
    float du = dl * uu;
    float acc = uu * Dpd;
    #pragma unroll
    for (int s=0;s<16;s++){
      float a = __expf(dl * Ac[s]);
      h[s] = fmaf(a, h[s], du * sB[nn][s]);
      acc = fmaf(h[s], sC[nn][s], acc);
    }
    sY[nn][tid] = acc;
  }
  __syncthreads();

  // LN + gate: wave w handles tokens t = w, w+6, ...
  const int wid = tid>>6, lane = tid&63;
  for (int t = wid; t < 32; t += 6){
    float v[6]; float s=0.f, s2=0.f;
    #pragma unroll
    for (int j=0;j<6;j++){
      v[j] = sY[t][lane + j*64];
      s += v[j]; s2 += v[j]*v[j];
    }
    #pragma unroll
    for (int off=32; off; off>>=1){ s += __shfl_xor(s, off); s2 += __shfl_xor(s2, off); }
    float m = s*(1.f/384.f);
    float rs = rsqrtf(s2*(1.f/384.f) - m*m + 1e-5f);
    #pragma unroll
    for (int j=0;j<6;j++){
      int cc = lane + j*64;
      float ly = (v[j]-m)*rs*lnw[cc] + lnb[cc];
      float zv = z[(size_t)(n0+t)*384 + cc];
      g_bf[(size_t)(n0+t)*384 + cc] = f2bf(ly * zv * sigmoidf_(zv));
    }
  }
}

// ---------------- Kernel 8 (MFMA): out = g @ W_out + x ----------------
__global__ __launch_bounds__(256) void k8_gemm2(
    const u16* __restrict__ g_bf, const u16* __restrict__ woutf,
    const float* __restrict__ x, float* __restrict__ out)
{
  __shared__ u16 sG[32][392];       // 24.5 KB, stride 784 B -> 2-way alias only
  const int tid = threadIdx.x;
  const int tok0 = blockIdx.x*32;
  for (int i = tid; i < 32*48; i += 256){
    int t = i/48, c8 = i%48;
    *(u16x8*)&sG[t][c8*8] = *(const u16x8*)(g_bf + (size_t)(tok0+t)*384 + c8*8);
  }
  __syncthreads();
  const int wid = tid>>6, lane = tid&63;
  const int wm = wid>>1, wn = wid&1;
  bf16x8 a[12];
  #pragma unroll
  for (int kt=0;kt<12;kt++)
    a[kt] = *(const bf16x8*)&sG[wm*16 + (lane&15)][kt*32 + ((lane>>4)<<3)];
  const bf16x8* wf = (const bf16x8*)woutf;
  const int r0 = tok0 + wm*16 + ((lane>>4)<<2);
  #pragma unroll
  for (int j=0;j<6;j++){
    int nt = wn*6 + j;
    f32x4 acc = (f32x4){0.f,0.f,0.f,0.f};
    const bf16x8* bp = wf + (size_t)nt*12*64 + lane;
    #pragma unroll
    for (int kt=0;kt<12;kt++)
      acc = __builtin_amdgcn_mfma_f32_16x16x32_bf16(a[kt], bp[kt*64], acc, 0,0,0);
    int col = nt*16 + (lane&15);
    #pragma unroll
    for (int r=0;r<4;r++){
      size_t o = (size_t)(r0+r)*192 + col;
      out[o] = acc[r] + x[o];
    }
  }
}

extern "C" void kernel_launch(void* const* d_in, const int* in_sizes, int n_in,
                              void* d_out, int out_size, void* d_ws, size_t ws_size,
                              hipStream_t stream) {
  const float* x      = (const float*)d_in[0];
  const float* ln_in_w= (const float*)d_in[1];
  const float* ln_in_b= (const float*)d_in[2];
  const float* W_in   = (const float*)d_in[3];
  const float* conv_w = (const float*)d_in[4];
  const float* conv_b = (const float*)d_in[5];
  const float* xpw    = (const float*)d_in[6];
  const float* dt_w   = (const float*)d_in[7];
  const float* dt_b   = (const float*)d_in[8];
  const float* A_log  = (const float*)d_in[9];
  const float* Dp     = (const float*)d_in[10];
  const float* ln_o_w = (const float*)d_in[11];
  const float* ln_o_b = (const float*)d_in[12];
  const float* W_out  = (const float*)d_in[13];
  float* out = (float*)d_out;

  float* ws = (float*)d_ws;
  const size_t NDI = (size_t)N_TOK * DI;       // 5,308,416
  float* xs   = ws;                 // N x 384
  float* z    = xs + NDI;           // N x 384
  float* u    = z  + NDI;           // N x 384
  float* dl   = u  + NDI;           // N x 384 (delta; aliased by g_bf after scan3 reads)
  float* Bc   = dl + NDI;           // N x 16
  float* Cc   = Bc + (size_t)N_TOK*DS;
  float* P    = Cc + (size_t)N_TOK*DS;          // NCHUNK x 6144 (aliased by winf before k34)
  float* he   = P  + (size_t)NCHUNK*DI*DS;
  float* hi   = he + (size_t)NCHUNK*DI*DS;
  u16*  winf  = (u16*)P;                         // 288 frags x 1 KB (dead once k1 done)
  u16*  woutf = (u16*)(hi + (size_t)NCHUNK*DI*DS); // 144 frags x 1 KB
  u16*  xpwf  = woutf + (size_t)144*512;         // 36 frags x 1 KB
  u16*  g_bf  = (u16*)dl;                        // N x 384 bf16 (delta dead after k67 scan)

  k0_prep        <<<117, 256, 0, stream>>>(W_in, W_out, xpw, winf, woutf, xpwf);
  k1_ln_gemm1    <<<N_TOK/32, 256, 0, stream>>>(x, ln_in_w, ln_in_b, winf, xs, z);
  k2_conv_silu   <<<(N_TOK*96)/256, 256, 0, stream>>>(xs, conv_w, conv_b, u);
  k34_xproj_scan1<<<NCHUNK, 384, 0, stream>>>(u, xpwf, dt_w, dt_b, A_log, dl, Bc, Cc, P, he);
  k5_scan2       <<<24, 256, 0, stream>>>(P, he, hi);
  k67_scan3_lngate<<<NCHUNK, 384, 0, stream>>>(dl, u, Bc, Cc, A_log, Dp, hi, z,
                                               ln_o_w, ln_o_b, g_bf);
  k8_gemm2       <<<N_TOK/32, 256, 0, stream>>>(g_bf, woutf, x, out);
}